// Round 7
// baseline (2735.580 us; speedup 1.0000x reference)
//
#include <hip/hip_runtime.h>

#define D 256
#define L_TOT 13294

typedef __attribute__((ext_vector_type(8))) __bf16 bf16x8;
typedef __attribute__((ext_vector_type(4))) float f32x4;
typedef __attribute__((ext_vector_type(2))) float f32x2;

__device__ __forceinline__ float bf2f(unsigned short u) {
    return __uint_as_float(((unsigned int)u) << 16);
}
__device__ __forceinline__ unsigned short f2bf(float f) {
    unsigned int u = __float_as_uint(f);
    u += 0x7FFFu + ((u >> 16) & 1u);   // round-to-nearest-even
    return (unsigned short)(u >> 16);
}
// two bf16 packed in a dword -> f32x2 {lo, hi}
__device__ __forceinline__ f32x2 bfpair(unsigned int d) {
    f32x2 r;
    r.x = __uint_as_float(d << 16);
    r.y = __uint_as_float(d & 0xFFFF0000u);
    return r;
}
__device__ __forceinline__ f32x2 fma2(f32x2 a, float w, f32x2 c) {
    return __builtin_elementwise_fma(a, (f32x2){w, w}, c);   // v_pk_fma_f32
}

// ---------------------------------------------------------------------------
// Dtype probe on level_embed: bf16 data -> ~100% sane exponents; fp32 read as
// halfwords -> ~60%. flag=1 means bf16 inputs.
// ---------------------------------------------------------------------------
__global__ void probe_k(const unsigned short* __restrict__ u, int n, int* __restrict__ flag)
{
    __shared__ int cnt;
    if (threadIdx.x == 0) cnt = 0;
    __syncthreads();
    int c = 0;
    for (int i = threadIdx.x; i < n; i += 256) {
        const int e = (u[i] >> 7) & 0xFF;
        if (e == 0 || (e >= 96 && e <= 150)) ++c;
    }
    atomicAdd(&cnt, c);
    __syncthreads();
    if (threadIdx.x == 0) *flag = (cnt * 10 > n * 9) ? 1 : 0;
}

__global__ __launch_bounds__(256) void convert_k(
    const void* __restrict__ src, unsigned short* __restrict__ dst, int n,
    const int* __restrict__ flag)
{
    const int i = blockIdx.x * 256 + threadIdx.x;
    if (i >= n) return;
    if (*flag) dst[i] = ((const unsigned short*)src)[i];
    else       dst[i] = f2bf(((const float*)src)[i]);
}

// Convert + transpose: src (L,K,N) -> dst (L,N,K) bf16.
__global__ __launch_bounds__(256) void convt_k(
    const void* __restrict__ src, unsigned short* __restrict__ dst,
    int K, int N, int L, const int* __restrict__ flag)
{
    const long e = (long)blockIdx.x * 256 + threadIdx.x;
    const long tot = (long)L * K * N;
    if (e >= tot) return;
    const int per = K * N;
    const int li = (int)(e / per);
    const int r  = (int)(e - (long)li * per);
    const int n  = r / K;
    const int k  = r - n * K;
    const long s = (long)li * per + (long)k * N + n;
    dst[e] = (*flag) ? ((const unsigned short*)src)[s]
                     : f2bf(((const float*)src)[s]);
}

// ---------------------------------------------------------------------------
// Flatten (B,D,H,W) src inputs -> state bf16 (tok,D).
// ---------------------------------------------------------------------------
__global__ __launch_bounds__(256) void flatten_k(
    const void* __restrict__ s0, const void* __restrict__ s1,
    const void* __restrict__ s2, const void* __restrict__ s3,
    const int* __restrict__ flag, unsigned short* __restrict__ state)
{
    const long e = (long)blockIdx.x * 256 + threadIdx.x;
    const int d = (int)(e & 255);
    const long tok = e >> 8;
    const int b = (int)(tok / L_TOT);
    const int t = (int)(tok - (long)b * L_TOT);
    const void *sp;
    int hw, idx;
    if (t < 10000)      { sp = s0; hw = 10000; idx = t;          }
    else if (t < 12500) { sp = s1; hw = 2500;  idx = t - 10000;  }
    else if (t < 13125) { sp = s2; hw = 625;   idx = t - 12500;  }
    else                { sp = s3; hw = 169;   idx = t - 13125;  }
    const long a = ((long)b * D + d) * hw + idx;
    state[e] = (*flag) ? ((const unsigned short*)sp)[a]
                       : f2bf(((const float*)sp)[a]);
}

// Layer-invariant pos precompute: posc = pos_input + level_embed (bf16).
__global__ __launch_bounds__(256) void posconst_k(
    const void* __restrict__ p0, const void* __restrict__ p1,
    const void* __restrict__ p2, const void* __restrict__ p3,
    const unsigned short* __restrict__ lev, const int* __restrict__ flag,
    unsigned short* __restrict__ posc)
{
    const long e = (long)blockIdx.x * 256 + threadIdx.x;
    const int d = (int)(e & 255);
    const long tok = e >> 8;
    const int b = (int)(tok / L_TOT);
    const int t = (int)(tok - (long)b * L_TOT);
    const void *pp;
    int hw, idx, l;
    if (t < 10000)      { pp = p0; hw = 10000; idx = t;          l = 0; }
    else if (t < 12500) { pp = p1; hw = 2500;  idx = t - 10000;  l = 1; }
    else if (t < 13125) { pp = p2; hw = 625;   idx = t - 12500;  l = 2; }
    else                { pp = p3; hw = 169;   idx = t - 13125;  l = 3; }
    const long a = ((long)b * D + d) * hw + idx;
    const float pv = (*flag) ? bf2f(((const unsigned short*)pp)[a])
                             : ((const float*)pp)[a];
    posc[e] = f2bf(pv + bf2f(lev[l * D + d]));
}

// q = x + posc, fully coalesced uint4 (8 bf16/thread). (layer-0 only)
__global__ __launch_bounds__(256) void addq_k(
    const unsigned short* __restrict__ x, const unsigned short* __restrict__ p,
    unsigned short* __restrict__ q, long n8)
{
    const long e = (long)blockIdx.x * 256 + threadIdx.x;
    if (e >= n8) return;
    const uint4 xv = ((const uint4*)x)[e];
    const uint4 pv = ((const uint4*)p)[e];
    uint4 o;
#define ADDPK(a, b) ({ const f32x2 fa = bfpair(a), fb = bfpair(b); \
        (unsigned int)f2bf(fb.x + fa.x) | ((unsigned int)f2bf(fb.y + fa.y) << 16); })
    o.x = ADDPK(xv.x, pv.x); o.y = ADDPK(xv.y, pv.y);
    o.z = ADDPK(xv.z, pv.z); o.w = ADDPK(xv.w, pv.w);
#undef ADDPK
    ((uint4*)q)[e] = o;
}

// Fallback (tight workspace): per-layer q = x + pos_input + level_embed.
__global__ __launch_bounds__(256) void posflat_k(
    const void* __restrict__ p0, const void* __restrict__ p1,
    const void* __restrict__ p2, const void* __restrict__ p3,
    const unsigned short* __restrict__ lev, const int* __restrict__ flag,
    const unsigned short* __restrict__ x, unsigned short* __restrict__ q)
{
    const long e = (long)blockIdx.x * 256 + threadIdx.x;
    const int d = (int)(e & 255);
    const long tok = e >> 8;
    const int b = (int)(tok / L_TOT);
    const int t = (int)(tok - (long)b * L_TOT);
    const void *pp;
    int hw, idx, l;
    if (t < 10000)      { pp = p0; hw = 10000; idx = t;          l = 0; }
    else if (t < 12500) { pp = p1; hw = 2500;  idx = t - 10000;  l = 1; }
    else if (t < 13125) { pp = p2; hw = 625;   idx = t - 12500;  l = 2; }
    else                { pp = p3; hw = 169;   idx = t - 13125;  l = 3; }
    const long a = ((long)b * D + d) * hw + idx;
    const float pv = (*flag) ? bf2f(((const unsigned short*)pp)[a])
                             : ((const float*)pp)[a];
    q[e] = f2bf(pv + bf2f(lev[l * D + d]) + bf2f(x[e]));
}

// ---------------------------------------------------------------------------
// MFMA GEMM core, 2-phase double-buffered with BK=32 (T3 minimum pipeline at
// UNCHANGED 32KB LDS -> occupancy stays 3 blocks/CU; R3's BK=64 dbuf needed
// 64KB and regressed). Per K-step: stage(next buf) -> compute(cur) ->
// 1 barrier (drains vmcnt): staged loads fly under the 16 MFMAs + ds_reads.
// Tile 128x128, 4 waves (2x2). OPERANDS SWAPPED: acc = mfma(bfr, af, acc) ->
// lane holds row (l&15), 4 consecutive cols (l>>4)*4+r -> ushort4 epilogue.
// BK=32 swizzle (64B rows, 4 groups): position p = cc ^ s(r),
// s(r) = (r&3)^((r>>2)&3) -> 2-way bank alias on ds_read_b128 (free, m136).
// Global source pre-swizzled with the same involution (rule #21).
// ---------------------------------------------------------------------------
template<bool RELU, bool RESID>
__device__ __forceinline__ void gemm_core(
    const unsigned short* __restrict__ A, int ldA,
    const unsigned short* __restrict__ Bt, int ldB,
    const unsigned short* __restrict__ bias,
    const unsigned short* resid,          // may alias out
    unsigned short* out, int ldO,
    long M, int K, int col0, long row0,
    unsigned short* As, unsigned short* Bs)   // each [2][128][32] = 8192 ush
{
    const int tid = threadIdx.x;
    const int l  = tid & 63;
    const int w  = tid >> 6;
    const int wm = w >> 1, wn = w & 1;

    f32x4 acc[4][4];
#pragma unroll
    for (int i = 0; i < 4; ++i)
#pragma unroll
        for (int j = 0; j < 4; ++j) acc[i][j] = (f32x4){0.f, 0.f, 0.f, 0.f};

    const int sr = tid >> 2;       // staging row within half-tile (0..63)
    const int sg = tid & 3;        // 16B group within 64B row

    auto stage = [&](int buf, int k0) {
#pragma unroll
        for (int i = 0; i < 2; ++i) {
            const int r = i * 64 + sr;
            long arow = row0 + r; if (arow >= M) arow = M - 1;   // clamp tail
            const int s = (r & 3) ^ ((r >> 2) & 3);
            const int ke = k0 + ((sg ^ s) << 3);                 // pre-swizzled src
            const unsigned short* ga = A  + arow * (long)ldA + ke;
            const unsigned short* gb = Bt + (long)(col0 + r) * ldB + ke;
            __builtin_amdgcn_global_load_lds(
                (const __attribute__((address_space(1))) void*)ga,
                (__attribute__((address_space(3))) void*)(As + buf * 4096 + i * 2048 + w * 512),
                16, 0, 0);
            __builtin_amdgcn_global_load_lds(
                (const __attribute__((address_space(1))) void*)gb,
                (__attribute__((address_space(3))) void*)(Bs + buf * 4096 + i * 2048 + w * 512),
                16, 0, 0);
        }
    };

    auto compute = [&](int buf) {
        const char* Ab = (const char*)As + buf * 8192;
        const char* Bb = (const char*)Bs + buf * 8192;
        const int cc = l >> 4;
        bf16x8 af[4], bfr[4];
#pragma unroll
        for (int mi = 0; mi < 4; ++mi) {
            const int ar = wm * 64 + mi * 16 + (l & 15);
            const int p = cc ^ ((ar & 3) ^ ((ar >> 2) & 3));
            af[mi] = *(const bf16x8*)(Ab + ar * 64 + (p << 4));
        }
#pragma unroll
        for (int ni = 0; ni < 4; ++ni) {
            const int br = wn * 64 + ni * 16 + (l & 15);
            const int p = cc ^ ((br & 3) ^ ((br >> 2) & 3));
            bfr[ni] = *(const bf16x8*)(Bb + br * 64 + (p << 4));
        }
#pragma unroll
        for (int mi = 0; mi < 4; ++mi)
#pragma unroll
            for (int ni = 0; ni < 4; ++ni)
                acc[mi][ni] = __builtin_amdgcn_mfma_f32_16x16x32_bf16(
                    bfr[ni], af[mi], acc[mi][ni], 0, 0, 0);   // SWAPPED -> C^T frag
    };

    stage(0, 0);
    __syncthreads();                 // buf0 ready
    int cur = 0;
    for (int k0 = 32; k0 < K; k0 += 32) {
        stage(cur ^ 1, k0);          // issue next-tile loads (fly under compute)
        compute(cur);
        __syncthreads();             // drains vmcnt: next buf ready, cur reusable
        cur ^= 1;
    }
    compute(cur);

    // epilogue: lane holds row (l&15), 4 consecutive cols (l>>4)*4+r
#pragma unroll
    for (int mi = 0; mi < 4; ++mi) {
        const long rr = row0 + wm * 64 + mi * 16 + (l & 15);
        if (rr >= M) continue;
#pragma unroll
        for (int ni = 0; ni < 4; ++ni) {
            const int col = col0 + wn * 64 + ni * 16 + (l >> 4) * 4;
            f32x4 v = acc[mi][ni];
            if (bias) {
                const ushort4 b4 = *(const ushort4*)(bias + col);
                v[0] += bf2f(b4.x); v[1] += bf2f(b4.y);
                v[2] += bf2f(b4.z); v[3] += bf2f(b4.w);
            }
            if (RELU) {
                v[0] = fmaxf(v[0], 0.f); v[1] = fmaxf(v[1], 0.f);
                v[2] = fmaxf(v[2], 0.f); v[3] = fmaxf(v[3], 0.f);
            }
            if (RESID) {
                const ushort4 r4 = *(const ushort4*)(resid + rr * (long)ldO + col);
                v[0] += bf2f(r4.x); v[1] += bf2f(r4.y);
                v[2] += bf2f(r4.z); v[3] += bf2f(r4.w);
            }
            ushort4 o;
            o.x = f2bf(v[0]); o.y = f2bf(v[1]); o.z = f2bf(v[2]); o.w = f2bf(v[3]);
            *(ushort4*)(out + rr * (long)ldO + col) = o;
        }
    }
}

template<bool RELU, bool RESID>
__global__ __launch_bounds__(256, 3) void mgemm_k(
    const unsigned short* __restrict__ A, int ldA,
    const unsigned short* __restrict__ Bt, int ldB,
    const unsigned short* __restrict__ bias,
    const unsigned short* resid,
    unsigned short* out, int ldOut,
    long M, int K)
{
    __shared__ unsigned short As[8192];
    __shared__ unsigned short Bs[8192];
    gemm_core<RELU, RESID>(A, ldA, Bt, ldB, bias, resid, out, ldOut,
                           M, K, blockIdx.x * 128, (long)blockIdx.y * 128, As, Bs);
}

// Merged value + sampling-offsets + attn-logits (one dispatch; segment select
// is block-uniform). grid = dim3(5, MB): cols 0-1 value, 2-3 offsets, 4 logits.
__global__ __launch_bounds__(256, 3) void mgemm3_k(
    const unsigned short* __restrict__ state, const unsigned short* __restrict__ q,
    const unsigned short* __restrict__ Wv,  const unsigned short* __restrict__ bv,
    const unsigned short* __restrict__ Wso, const unsigned short* __restrict__ bso,
    const unsigned short* __restrict__ Waw, const unsigned short* __restrict__ baw,
    unsigned short* valo, unsigned short* offo, unsigned short* awo, long M)
{
    __shared__ unsigned short As[8192];
    __shared__ unsigned short Bs[8192];
    const int cx = blockIdx.x * 128;
    const long row0 = (long)blockIdx.y * 128;
    if (cx < 256)
        gemm_core<false, false>(state, D, Wv, D, bv, nullptr, valo, D,
                                M, D, cx, row0, As, Bs);
    else if (cx < 512)
        gemm_core<false, false>(q, D, Wso, D, bso, nullptr, offo, D,
                                M, D, cx - 256, row0, As, Bs);
    else
        gemm_core<false, false>(q, D, Waw, D, baw, nullptr, awo, 128,
                                M, D, 0, row0, As, Bs);
}

// ---------------------------------------------------------------------------
// Deformable sampling. One block per token, XCD-AWARE TOKEN SWIZZLE (T1,
// bijective q/r form): consecutive tokens are spatial neighbors sharing
// corner rows; default round-robin puts neighbors on different XCD L2s ->
// 126MB HBM fetch vs 27MB of val (4.7x over-fetch). Chunking tokens per XCD
// makes each XCD's working set ~3.4MB (L2-fits).
// Prep (tid<128, u=h*16+lp): tables at [mu=lp*8+h][c ^ (lp&3)] (4-way write
// conflict, pair-preserving XOR; gather sums over corners so no unpermute).
// Gather: tid = g*64+h*8+q; int4/float4 table reads, 4 unconditional uint2
// loads/j + packed f32x2 fma. Cross-wave reduce via [3][4][64] LDS.
// ---------------------------------------------------------------------------
__global__ __launch_bounds__(256) void sample_k(
    const unsigned short* __restrict__ off, const unsigned short* __restrict__ aw,
    const unsigned short* __restrict__ val, unsigned short* __restrict__ attn)
{
    __shared__ __align__(16) int   cidx[128][4];   // byte offsets into val rows
    __shared__ __align__(16) float cw[128][4];
    __shared__ float red[3][4][64];
    // bijective XCD chunking: bid -> (xcd = bid%8, i = bid/8)
    const int nwg = (int)gridDim.x;
    const int bid = (int)blockIdx.x;
    const int qn = nwg >> 3, rn = nwg & 7;
    const int xcd = bid & 7;
    const int base = (xcd < rn) ? xcd * (qn + 1) : rn * (qn + 1) + (xcd - rn) * qn;
    const long tok = (long)base + (bid >> 3);
    const int tid = threadIdx.x;
    const int b = (int)(tok / L_TOT);
    const int t = (int)(tok - (long)b * L_TOT);

    if (tid < 128) {
        const int u = tid;                       // u = h*16 + lp
        const int lp = u & 15;
        const int mu = lp * 8 + (u >> 4);        // [lp*8+h]
        const int cswz = lp & 3;                 // pair-preserving bank swizzle
        // softmax over the 16 samples of this head (16-lane shfl groups)
        const float logit = bf2f(aw[tok * 128 + u]);
        float m = logit;
#pragma unroll
        for (int mk = 1; mk < 16; mk <<= 1) m = fmaxf(m, __shfl_xor(m, mk));
        const float e = expf(logit - m);
        float s = e;
#pragma unroll
        for (int mk = 1; mk < 16; mk <<= 1) s += __shfl_xor(s, mk);
        const float a = e / s;
        // token geometry
        int st0, W0;
        if (t < 10000)      { st0 = 0;     W0 = 100; }
        else if (t < 12500) { st0 = 10000; W0 = 50;  }
        else if (t < 13125) { st0 = 12500; W0 = 25;  }
        else                { st0 = 13125; W0 = 13;  }
        const int i0 = t - st0;
        const int yy = i0 / W0;
        const int xx = i0 - yy * W0;
        const float gx = (xx + 0.5f) / (float)W0;
        const float gy = (yy + 0.5f) / (float)W0;   // square levels
        // sample level
        const int lv = (u >> 2) & 3;
        const int Wv  = (lv == 0) ? 100 : (lv == 1) ? 50 : (lv == 2) ? 25 : 13;
        const int stl = (lv == 0) ? 0 : (lv == 1) ? 10000 : (lv == 2) ? 12500 : 13125;
        const unsigned int op = *(const unsigned int*)(off + tok * 256 + 2 * u);
        const float ox = bf2f((unsigned short)op);
        const float oy = bf2f((unsigned short)(op >> 16));
        const float px = (gx + ox / (float)Wv) * Wv - 0.5f;
        const float py = (gy + oy / (float)Wv) * Wv - 0.5f;
        const float fx = floorf(px), fy = floorf(py);
        const float wx1 = px - fx, wy1 = py - fy;
        const int x0 = (int)fx, y0 = (int)fy;
#pragma unroll
        for (int c = 0; c < 4; ++c) {
            const int xi = x0 + (c & 1);
            const int yi = y0 + (c >> 1);
            const float wgt = ((c & 1) ? wx1 : 1.f - wx1) * ((c >> 1) ? wy1 : 1.f - wy1);
            const bool ok = (xi >= 0) && (xi < Wv) && (yi >= 0) && (yi < Wv);
            cidx[mu][c ^ cswz] = ok ? ((stl + yi * Wv + xi) << 9) : 0;   // *512 B
            cw[mu][c ^ cswz]   = ok ? wgt * a : 0.f;
        }
    }
    __syncthreads();
    const int g = tid >> 6;                 // sample group (= wave)
    const int l = tid & 63;
    const int h = l >> 3;                   // head
    const int q = l & 7;                    // channel quad
    const char* vb = (const char*)val + ((long)b * L_TOT) * 512 + h * 64 + q * 8;
    f32x2 A01 = {0.f, 0.f}, A23 = {0.f, 0.f};
#pragma unroll
    for (int j = 0; j < 4; ++j) {
        const int mu = (j * 4 + g) * 8 + h;
        const int4   ci = *(const int4*)(&cidx[mu][0]);
        const float4 wv = *(const float4*)(&cw[mu][0]);
        const uint2 d0 = *(const uint2*)(vb + ci.x);
        const uint2 d1 = *(const uint2*)(vb + ci.y);
        const uint2 d2 = *(const uint2*)(vb + ci.z);
        const uint2 d3 = *(const uint2*)(vb + ci.w);
        A01 = fma2(bfpair(d0.x), wv.x, A01);  A23 = fma2(bfpair(d0.y), wv.x, A23);
        A01 = fma2(bfpair(d1.x), wv.y, A01);  A23 = fma2(bfpair(d1.y), wv.y, A23);
        A01 = fma2(bfpair(d2.x), wv.z, A01);  A23 = fma2(bfpair(d2.y), wv.z, A23);
        A01 = fma2(bfpair(d3.x), wv.w, A01);  A23 = fma2(bfpair(d3.y), wv.w, A23);
    }
    if (g) {
        red[g - 1][0][l] = A01.x; red[g - 1][1][l] = A01.y;
        red[g - 1][2][l] = A23.x; red[g - 1][3][l] = A23.y;
    }
    __syncthreads();
    if (g == 0) {
        float a0 = A01.x, a1 = A01.y, a2 = A23.x, a3 = A23.y;
#pragma unroll
        for (int p = 0; p < 3; ++p) {
            a0 += red[p][0][l]; a1 += red[p][1][l];
            a2 += red[p][2][l]; a3 += red[p][3][l];
        }
        ushort4 o;
        o.x = f2bf(a0); o.y = f2bf(a1); o.z = f2bf(a2); o.w = f2bf(a3);
        *(ushort4*)(attn + tok * 256 + h * 32 + q * 4) = o;
    }
}

// ---------------------------------------------------------------------------
// LayerNorm over D=256. Block = 4 waves = 4 tokens; lane = 4 channels.
// QOUT: also emit q = bf16(out) + posc (bit-exact with the old addq pass).
// ---------------------------------------------------------------------------
template<bool QOUT>
__global__ __launch_bounds__(256) void ln_k(
    const unsigned short* __restrict__ y,
    const unsigned short* __restrict__ g, const unsigned short* __restrict__ bb,
    unsigned short* __restrict__ out,
    const unsigned short* __restrict__ posc, unsigned short* __restrict__ qout,
    long nt)
{
    const int wv = threadIdx.x >> 6;
    const int lane = threadIdx.x & 63;
    const long tok = (long)blockIdx.x * 4 + wv;
    if (tok >= nt) return;
    const ushort4 v4 = *(const ushort4*)(y + tok * D + lane * 4);
    const float v0 = bf2f(v4.x), v1 = bf2f(v4.y), v2 = bf2f(v4.z), v3 = bf2f(v4.w);
    float s = v0 + v1 + v2 + v3;
#pragma unroll
    for (int m = 1; m < 64; m <<= 1) s += __shfl_xor(s, m);
    const float mean = s * (1.f / D);
    const float d0 = v0 - mean, d1 = v1 - mean, d2 = v2 - mean, d3 = v3 - mean;
    float q = d0 * d0 + d1 * d1 + d2 * d2 + d3 * d3;
#pragma unroll
    for (int m = 1; m < 64; m <<= 1) q += __shfl_xor(q, m);
    const float rstd = rsqrtf(q * (1.f / D) + 1e-5f);
    const int c0 = lane * 4;
    ushort4 o;
    o.x = f2bf(d0 * rstd * bf2f(g[c0 + 0]) + bf2f(bb[c0 + 0]));
    o.y = f2bf(d1 * rstd * bf2f(g[c0 + 1]) + bf2f(bb[c0 + 1]));
    o.z = f2bf(d2 * rstd * bf2f(g[c0 + 2]) + bf2f(bb[c0 + 2]));
    o.w = f2bf(d3 * rstd * bf2f(g[c0 + 3]) + bf2f(bb[c0 + 3]));
    *(ushort4*)(out + tok * D + c0) = o;
    if (QOUT) {
        const ushort4 p4 = *(const ushort4*)(posc + tok * D + c0);
        ushort4 qo;
        qo.x = f2bf(bf2f(o.x) + bf2f(p4.x));
        qo.y = f2bf(bf2f(o.y) + bf2f(p4.y));
        qo.z = f2bf(bf2f(o.z) + bf2f(p4.z));
        qo.w = f2bf(bf2f(o.w) + bf2f(p4.w));
        *(ushort4*)(qout + tok * D + c0) = qo;
    }
}

// ---------------------------------------------------------------------------
// Finalize: OUTPUT IS FP32.
// ---------------------------------------------------------------------------
__global__ __launch_bounds__(256) void finalize_k(
    const unsigned short* __restrict__ state, float* __restrict__ out, long osz)
{
    const long e = (long)blockIdx.x * 256 + threadIdx.x;
    const long n0 = osz - 4;
    if (e < n0) out[e] = bf2f(state[e]);
    if (e < 4) {
        const float st[4] = {0.f, 10000.f, 12500.f, 13125.f};
        out[n0 + e] = st[e];
    }
}

extern "C" void kernel_launch(void* const* d_in, const int* in_sizes, int n_in,
                              void* d_out, int out_size, void* d_ws, size_t ws_size,
                              hipStream_t stream)
{
    (void)n_in;
    const long osz = (long)out_size;
    const long nt = (osz - 4) / D;                      // total tokens
    const int nlayers = in_sizes[9] / (D * D);          // so_w: (NL, 256, 256)
    const int dff = in_sizes[19] / (nlayers * D);       // f1_w: (NL, 256, DFF)

    char* ws = (char*)d_ws;
    int* flag = (int*)ws;  ws += 256;
    unsigned short* wc = (unsigned short*)ws;           // canonical bf16 weights
    long off[25]; long acc_off = 0;
    for (int i = 8; i <= 24; ++i) { off[i] = acc_off; acc_off += in_sizes[i]; }
    ws += ((acc_off * 2 + 255) / 256) * 256;
    const size_t SZ_BF = (size_t)nt * D * 2;
    unsigned short* state     = (unsigned short*)ws;  ws += SZ_BF;  // running src
    unsigned short* val_b     = (unsigned short*)ws;  ws += SZ_BF;  // value / h lo
    unsigned short* offy_b    = (unsigned short*)ws;  ws += SZ_BF;  // offsets,y / h hi
    unsigned short* posattn_b = (unsigned short*)ws;  ws += SZ_BF;  // q, attn, ffn part
    unsigned short* aw_b      = (unsigned short*)ws;  ws += (size_t)nt * 128 * 2;
    unsigned short* hbuf = val_b;   // [nt][dff/2] spans val_b..offy_b (contiguous)

    // optional +27 MB: layer-invariant pos buffer (guarded by ws_size)
    const size_t used_base = (size_t)((char*)aw_b - (char*)d_ws) + (size_t)nt * 128 * 2;
    const bool have_posc = (ws_size >= used_base + SZ_BF);
    unsigned short* posc = (unsigned short*)((char*)d_ws + used_base);

    probe_k<<<1, 256, 0, stream>>>((const unsigned short*)d_in[8], in_sizes[8], flag);

    // vectors/biases: plain convert
    const int vecIdx[11] = {8, 10, 12, 14, 16, 17, 18, 20, 22, 23, 24};
    for (int j = 0; j < 11; ++j) {
        const int i = vecIdx[j];
        convert_k<<<(in_sizes[i] + 255) / 256, 256, 0, stream>>>(
            d_in[i], wc + off[i], in_sizes[i], flag);
    }
    // matrices: convert + transpose to [N][K] for MFMA B-fragments
    const int matIdx[6] = {9, 11, 13, 15, 19, 21};
    const int matK[6]   = {D, D, D, D, D, dff};
    const int matN[6]   = {D, 128, D, D, dff, D};
    for (int j = 0; j < 6; ++j) {
        const int i = matIdx[j];
        convt_k<<<(in_sizes[i] + 255) / 256, 256, 0, stream>>>(
            d_in[i], wc + off[i], matK[j], matN[j], nlayers, flag);
    }

    flatten_k<<<(int)nt, 256, 0, stream>>>(
        d_in[0], d_in[2], d_in[4], d_in[6], flag, state);
    if (have_posc)
        posconst_k<<<(int)nt, 256, 0, stream>>>(
            d_in[1], d_in[3], d_in[5], d_in[7], wc + off[8], flag, posc);

    const int MB = (int)((nt + 127) / 128);
    const int LB = (int)((nt + 3) / 4);
    const long n8 = (long)nt * D / 8;
    const int AB = (int)((n8 + 255) / 256);
    const int dh = dff / 2;                     // 512: FFN split, h fits 2 buffers

    if (have_posc)                              // layer-0 q
        addq_k<<<AB, 256, 0, stream>>>(state, posc, posattn_b, n8);

    for (int i = 0; i < nlayers; ++i) {
        if (!have_posc)
            posflat_k<<<(int)nt, 256, 0, stream>>>(
                d_in[1], d_in[3], d_in[5], d_in[7], wc + off[8], flag, state, posattn_b);
        // merged: value (cols 0-255) | offsets (256-511) | logits (512-639)
        mgemm3_k<<<dim3(5, MB), 256, 0, stream>>>(
            state, posattn_b,
            wc + off[13] + (long)i * D * D,   wc + off[14] + i * D,
            wc + off[9]  + (long)i * D * 256, wc + off[10] + i * 256,
            wc + off[11] + (long)i * D * 128, wc + off[12] + i * 128,
            val_b, offy_b, aw_b, nt);
        sample_k<<<(int)nt, 256, 0, stream>>>(offy_b, aw_b, val_b, posattn_b);
        mgemm_k<false, true><<<dim3(2, MB), 256, 0, stream>>>(  // out-proj + resid
            posattn_b, D, wc + off[15] + (long)i * D * D, D, wc + off[16] + i * D,
            state, offy_b, D, nt, D);
        ln_k<false><<<LB, 256, 0, stream>>>(offy_b, wc + off[17] + i * D,
            wc + off[18] + i * D, state, nullptr, nullptr, nt);
        // FFN as 2 half-dff passes
        mgemm_k<true, false><<<dim3(dh / 128, MB), 256, 0, stream>>>(
            state, D, wc + off[19] + (long)i * D * dff, D, wc + off[20] + i * dff,
            nullptr, hbuf, dh, nt, D);
        mgemm_k<false, true><<<dim3(2, MB), 256, 0, stream>>>(
            hbuf, dh, wc + off[21] + (long)i * dff * D, dff, wc + off[22] + i * D,
            state, posattn_b, D, nt, dh);
        mgemm_k<true, false><<<dim3(dh / 128, MB), 256, 0, stream>>>(
            state, D, wc + off[19] + (long)i * D * dff + (long)dh * D, D,
            wc + off[20] + i * dff + dh, nullptr, hbuf, dh, nt, D);
        mgemm_k<false, true><<<dim3(2, MB), 256, 0, stream>>>(
            hbuf, dh, wc + off[21] + (long)i * dff * D + dh, dff, nullptr,
            posattn_b, posattn_b, D, nt, dh);
        // ln2; for all but last layer also emit next-layer q = bf16(out)+posc
        if (have_posc && i + 1 < nlayers)
            ln_k<true><<<LB, 256, 0, stream>>>(posattn_b, wc + off[23] + i * D,
                wc + off[24] + i * D, state, posc, posattn_b, nt);
        else
            ln_k<false><<<LB, 256, 0, stream>>>(posattn_b, wc + off[23] + i * D,
                wc + off[24] + i * D, state, nullptr, nullptr, nt);
    }

    finalize_k<<<(int)((osz - 4 + 255) / 256), 256, 0, stream>>>(
        state, (float*)d_out, osz);
}

// Round 8
// 2478.732 us; speedup vs baseline: 1.1036x; 1.1036x over previous
//
#include <hip/hip_runtime.h>

#define D 256
#define L_TOT 13294

typedef __attribute__((ext_vector_type(8))) __bf16 bf16x8;
typedef __attribute__((ext_vector_type(4))) float f32x4;
typedef __attribute__((ext_vector_type(2))) float f32x2;

__device__ __forceinline__ float bf2f(unsigned short u) {
    return __uint_as_float(((unsigned int)u) << 16);
}
__device__ __forceinline__ unsigned short f2bf(float f) {
    unsigned int u = __float_as_uint(f);
    u += 0x7FFFu + ((u >> 16) & 1u);   // round-to-nearest-even
    return (unsigned short)(u >> 16);
}
// two bf16 packed in a dword -> f32x2 {lo, hi}
__device__ __forceinline__ f32x2 bfpair(unsigned int d) {
    f32x2 r;
    r.x = __uint_as_float(d << 16);
    r.y = __uint_as_float(d & 0xFFFF0000u);
    return r;
}
__device__ __forceinline__ f32x2 fma2(f32x2 a, float w, f32x2 c) {
    return __builtin_elementwise_fma(a, (f32x2){w, w}, c);   // v_pk_fma_f32
}

// ---------------------------------------------------------------------------
// Dtype probe on level_embed: bf16 data -> ~100% sane exponents; fp32 read as
// halfwords -> ~60%. flag=1 means bf16 inputs.
// ---------------------------------------------------------------------------
__global__ void probe_k(const unsigned short* __restrict__ u, int n, int* __restrict__ flag)
{
    __shared__ int cnt;
    if (threadIdx.x == 0) cnt = 0;
    __syncthreads();
    int c = 0;
    for (int i = threadIdx.x; i < n; i += 256) {
        const int e = (u[i] >> 7) & 0xFF;
        if (e == 0 || (e >= 96 && e <= 150)) ++c;
    }
    atomicAdd(&cnt, c);
    __syncthreads();
    if (threadIdx.x == 0) *flag = (cnt * 10 > n * 9) ? 1 : 0;
}

__global__ __launch_bounds__(256) void convert_k(
    const void* __restrict__ src, unsigned short* __restrict__ dst, int n,
    const int* __restrict__ flag)
{
    const int i = blockIdx.x * 256 + threadIdx.x;
    if (i >= n) return;
    if (*flag) dst[i] = ((const unsigned short*)src)[i];
    else       dst[i] = f2bf(((const float*)src)[i]);
}

// Convert + transpose: src (L,K,N) -> dst (L,N,K) bf16.
__global__ __launch_bounds__(256) void convt_k(
    const void* __restrict__ src, unsigned short* __restrict__ dst,
    int K, int N, int L, const int* __restrict__ flag)
{
    const long e = (long)blockIdx.x * 256 + threadIdx.x;
    const long tot = (long)L * K * N;
    if (e >= tot) return;
    const int per = K * N;
    const int li = (int)(e / per);
    const int r  = (int)(e - (long)li * per);
    const int n  = r / K;
    const int k  = r - n * K;
    const long s = (long)li * per + (long)k * N + n;
    dst[e] = (*flag) ? ((const unsigned short*)src)[s]
                     : f2bf(((const float*)src)[s]);
}

// ---------------------------------------------------------------------------
// Flatten (B,D,H,W) src inputs -> state bf16 (tok,D).
// ---------------------------------------------------------------------------
__global__ __launch_bounds__(256) void flatten_k(
    const void* __restrict__ s0, const void* __restrict__ s1,
    const void* __restrict__ s2, const void* __restrict__ s3,
    const int* __restrict__ flag, unsigned short* __restrict__ state)
{
    const long e = (long)blockIdx.x * 256 + threadIdx.x;
    const int d = (int)(e & 255);
    const long tok = e >> 8;
    const int b = (int)(tok / L_TOT);
    const int t = (int)(tok - (long)b * L_TOT);
    const void *sp;
    int hw, idx;
    if (t < 10000)      { sp = s0; hw = 10000; idx = t;          }
    else if (t < 12500) { sp = s1; hw = 2500;  idx = t - 10000;  }
    else if (t < 13125) { sp = s2; hw = 625;   idx = t - 12500;  }
    else                { sp = s3; hw = 169;   idx = t - 13125;  }
    const long a = ((long)b * D + d) * hw + idx;
    state[e] = (*flag) ? ((const unsigned short*)sp)[a]
                       : f2bf(((const float*)sp)[a]);
}

// Layer-invariant pos precompute: posc = pos_input + level_embed (bf16).
__global__ __launch_bounds__(256) void posconst_k(
    const void* __restrict__ p0, const void* __restrict__ p1,
    const void* __restrict__ p2, const void* __restrict__ p3,
    const unsigned short* __restrict__ lev, const int* __restrict__ flag,
    unsigned short* __restrict__ posc)
{
    const long e = (long)blockIdx.x * 256 + threadIdx.x;
    const int d = (int)(e & 255);
    const long tok = e >> 8;
    const int b = (int)(tok / L_TOT);
    const int t = (int)(tok - (long)b * L_TOT);
    const void *pp;
    int hw, idx, l;
    if (t < 10000)      { pp = p0; hw = 10000; idx = t;          l = 0; }
    else if (t < 12500) { pp = p1; hw = 2500;  idx = t - 10000;  l = 1; }
    else if (t < 13125) { pp = p2; hw = 625;   idx = t - 12500;  l = 2; }
    else                { pp = p3; hw = 169;   idx = t - 13125;  l = 3; }
    const long a = ((long)b * D + d) * hw + idx;
    const float pv = (*flag) ? bf2f(((const unsigned short*)pp)[a])
                             : ((const float*)pp)[a];
    posc[e] = f2bf(pv + bf2f(lev[l * D + d]));
}

// q = x + posc, fully coalesced uint4 (8 bf16/thread). (layer-0 only)
__global__ __launch_bounds__(256) void addq_k(
    const unsigned short* __restrict__ x, const unsigned short* __restrict__ p,
    unsigned short* __restrict__ q, long n8)
{
    const long e = (long)blockIdx.x * 256 + threadIdx.x;
    if (e >= n8) return;
    const uint4 xv = ((const uint4*)x)[e];
    const uint4 pv = ((const uint4*)p)[e];
    uint4 o;
#define ADDPK(a, b) ({ const f32x2 fa = bfpair(a), fb = bfpair(b); \
        (unsigned int)f2bf(fb.x + fa.x) | ((unsigned int)f2bf(fb.y + fa.y) << 16); })
    o.x = ADDPK(xv.x, pv.x); o.y = ADDPK(xv.y, pv.y);
    o.z = ADDPK(xv.z, pv.z); o.w = ADDPK(xv.w, pv.w);
#undef ADDPK
    ((uint4*)q)[e] = o;
}

// Fallback (tight workspace): per-layer q = x + pos_input + level_embed.
__global__ __launch_bounds__(256) void posflat_k(
    const void* __restrict__ p0, const void* __restrict__ p1,
    const void* __restrict__ p2, const void* __restrict__ p3,
    const unsigned short* __restrict__ lev, const int* __restrict__ flag,
    const unsigned short* __restrict__ x, unsigned short* __restrict__ q)
{
    const long e = (long)blockIdx.x * 256 + threadIdx.x;
    const int d = (int)(e & 255);
    const long tok = e >> 8;
    const int b = (int)(tok / L_TOT);
    const int t = (int)(tok - (long)b * L_TOT);
    const void *pp;
    int hw, idx, l;
    if (t < 10000)      { pp = p0; hw = 10000; idx = t;          l = 0; }
    else if (t < 12500) { pp = p1; hw = 2500;  idx = t - 10000;  l = 1; }
    else if (t < 13125) { pp = p2; hw = 625;   idx = t - 12500;  l = 2; }
    else                { pp = p3; hw = 169;   idx = t - 13125;  l = 3; }
    const long a = ((long)b * D + d) * hw + idx;
    const float pv = (*flag) ? bf2f(((const unsigned short*)pp)[a])
                             : ((const float*)pp)[a];
    q[e] = f2bf(pv + bf2f(lev[l * D + d]) + bf2f(x[e]));
}

// ---------------------------------------------------------------------------
// MFMA GEMM core, single-buffered m97 structure, BK=64 (R7 post-mortem:
// BK=32 dbuf halved MFMA-per-phase and regressed ~120us; R3: BK=64 dbuf cost
// occupancy. Single-buffer BK=64 at 32KB LDS / 3 blocks/CU is the measured
// optimum). Tile 128x128, 4 waves (2x2). OPERANDS SWAPPED:
// acc = mfma(bfr, af, acc) -> lane holds row (l&15), 4 consecutive cols
// (l>>4)*4+r -> ushort4 epilogue (R6: this was worth ~300us vs 2B scatter).
// LDS XOR-swizzle in 16B groups (G4); global source pre-swizzled (rule #21).
// ---------------------------------------------------------------------------
template<bool RELU, bool RESID>
__device__ __forceinline__ void gemm_core(
    const unsigned short* __restrict__ A, int ldA,
    const unsigned short* __restrict__ Bt, int ldB,
    const unsigned short* __restrict__ bias,
    const unsigned short* resid,          // may alias out
    unsigned short* out, int ldO,
    long M, int K, int col0, long row0,
    unsigned short* As, unsigned short* Bs)
{
    const int tid = threadIdx.x;
    const int l  = tid & 63;
    const int w  = tid >> 6;
    const int wm = w >> 1, wn = w & 1;

    f32x4 acc[4][4];
#pragma unroll
    for (int i = 0; i < 4; ++i)
#pragma unroll
        for (int j = 0; j < 4; ++j) acc[i][j] = (f32x4){0.f, 0.f, 0.f, 0.f};

    const int sr = tid >> 3;
    const int sg = tid & 7;

    for (int k0 = 0; k0 < K; k0 += 64) {
#pragma unroll
        for (int i = 0; i < 4; ++i) {
            const int r = i * 32 + sr;
            long arow = row0 + r; if (arow >= M) arow = M - 1;   // clamp tail
            const int ke = k0 + ((sg ^ (r & 7)) << 3);           // pre-swizzled src
            const unsigned short* ga = A  + arow * (long)ldA + ke;
            const unsigned short* gb = Bt + (long)(col0 + r) * ldB + ke;
            __builtin_amdgcn_global_load_lds(
                (const __attribute__((address_space(1))) void*)ga,
                (__attribute__((address_space(3))) void*)(As + i * 2048 + w * 512),
                16, 0, 0);
            __builtin_amdgcn_global_load_lds(
                (const __attribute__((address_space(1))) void*)gb,
                (__attribute__((address_space(3))) void*)(Bs + i * 2048 + w * 512),
                16, 0, 0);
        }
        __syncthreads();    // drains vmcnt, tiles ready
#pragma unroll
        for (int ks = 0; ks < 2; ++ks) {
            const int cc  = ks * 4 + (l >> 4);
            const int swz = ((cc ^ (l & 7)) << 4);
            bf16x8 af[4], bfr[4];
#pragma unroll
            for (int mi = 0; mi < 4; ++mi) {
                const int ar = wm * 64 + mi * 16 + (l & 15);
                af[mi] = *(const bf16x8*)((const char*)As + ar * 128 + swz);
            }
#pragma unroll
            for (int ni = 0; ni < 4; ++ni) {
                const int br = wn * 64 + ni * 16 + (l & 15);
                bfr[ni] = *(const bf16x8*)((const char*)Bs + br * 128 + swz);
            }
#pragma unroll
            for (int mi = 0; mi < 4; ++mi)
#pragma unroll
                for (int ni = 0; ni < 4; ++ni)
                    acc[mi][ni] = __builtin_amdgcn_mfma_f32_16x16x32_bf16(
                        bfr[ni], af[mi], acc[mi][ni], 0, 0, 0);   // SWAPPED -> C^T frag
        }
        __syncthreads();    // compute done before next stage overwrites
    }

    // epilogue: lane holds row (l&15), 4 consecutive cols (l>>4)*4+r
#pragma unroll
    for (int mi = 0; mi < 4; ++mi) {
        const long rr = row0 + wm * 64 + mi * 16 + (l & 15);
        if (rr >= M) continue;
#pragma unroll
        for (int ni = 0; ni < 4; ++ni) {
            const int col = col0 + wn * 64 + ni * 16 + (l >> 4) * 4;
            f32x4 v = acc[mi][ni];
            if (bias) {
                const ushort4 b4 = *(const ushort4*)(bias + col);
                v[0] += bf2f(b4.x); v[1] += bf2f(b4.y);
                v[2] += bf2f(b4.z); v[3] += bf2f(b4.w);
            }
            if (RELU) {
                v[0] = fmaxf(v[0], 0.f); v[1] = fmaxf(v[1], 0.f);
                v[2] = fmaxf(v[2], 0.f); v[3] = fmaxf(v[3], 0.f);
            }
            if (RESID) {
                const ushort4 r4 = *(const ushort4*)(resid + rr * (long)ldO + col);
                v[0] += bf2f(r4.x); v[1] += bf2f(r4.y);
                v[2] += bf2f(r4.z); v[3] += bf2f(r4.w);
            }
            ushort4 o;
            o.x = f2bf(v[0]); o.y = f2bf(v[1]); o.z = f2bf(v[2]); o.w = f2bf(v[3]);
            *(ushort4*)(out + rr * (long)ldO + col) = o;
        }
    }
}

template<bool RELU, bool RESID>
__global__ __launch_bounds__(256, 3) void mgemm_k(
    const unsigned short* __restrict__ A, int ldA,
    const unsigned short* __restrict__ Bt, int ldB,
    const unsigned short* __restrict__ bias,
    const unsigned short* resid,
    unsigned short* out, int ldOut,
    long M, int K)
{
    __shared__ unsigned short As[8192];
    __shared__ unsigned short Bs[8192];
    gemm_core<RELU, RESID>(A, ldA, Bt, ldB, bias, resid, out, ldOut,
                           M, K, blockIdx.x * 128, (long)blockIdx.y * 128, As, Bs);
}

// Merged value + sampling-offsets + attn-logits (one dispatch; segment select
// is block-uniform). grid = dim3(5, MB): cols 0-1 value, 2-3 offsets, 4 logits.
__global__ __launch_bounds__(256, 3) void mgemm3_k(
    const unsigned short* __restrict__ state, const unsigned short* __restrict__ q,
    const unsigned short* __restrict__ Wv,  const unsigned short* __restrict__ bv,
    const unsigned short* __restrict__ Wso, const unsigned short* __restrict__ bso,
    const unsigned short* __restrict__ Waw, const unsigned short* __restrict__ baw,
    unsigned short* valo, unsigned short* offo, unsigned short* awo, long M)
{
    __shared__ unsigned short As[8192];
    __shared__ unsigned short Bs[8192];
    const int cx = blockIdx.x * 128;
    const long row0 = (long)blockIdx.y * 128;
    if (cx < 256)
        gemm_core<false, false>(state, D, Wv, D, bv, nullptr, valo, D,
                                M, D, cx, row0, As, Bs);
    else if (cx < 512)
        gemm_core<false, false>(q, D, Wso, D, bso, nullptr, offo, D,
                                M, D, cx - 256, row0, As, Bs);
    else
        gemm_core<false, false>(q, D, Waw, D, baw, nullptr, awo, 128,
                                M, D, 0, row0, As, Bs);
}

// ---------------------------------------------------------------------------
// Deformable sampling. One block per token (R7 post-mortem: XCD token swizzle
// halved HBM fetch but sample is VALU-bound -> time +2%; reverted).
// Prep (tid<128, u=h*16+lp): tables at [mu=lp*8+h][c ^ (lp&3)] (4-way write
// conflict, pair-preserving XOR; gather sums over corners so no unpermute).
// Gather: tid = g*64+h*8+q; int4/float4 table reads, 4 unconditional uint2
// loads/j + packed f32x2 fma. Cross-wave reduce via [3][4][64] LDS.
// ---------------------------------------------------------------------------
__global__ __launch_bounds__(256) void sample_k(
    const unsigned short* __restrict__ off, const unsigned short* __restrict__ aw,
    const unsigned short* __restrict__ val, unsigned short* __restrict__ attn)
{
    __shared__ __align__(16) int   cidx[128][4];   // byte offsets into val rows
    __shared__ __align__(16) float cw[128][4];
    __shared__ float red[3][4][64];
    const long tok = blockIdx.x;
    const int tid = threadIdx.x;
    const int b = (int)(tok / L_TOT);
    const int t = (int)(tok - (long)b * L_TOT);

    if (tid < 128) {
        const int u = tid;                       // u = h*16 + lp
        const int lp = u & 15;
        const int mu = lp * 8 + (u >> 4);        // [lp*8+h]
        const int cswz = lp & 3;                 // pair-preserving bank swizzle
        // softmax over the 16 samples of this head (16-lane shfl groups)
        const float logit = bf2f(aw[tok * 128 + u]);
        float m = logit;
#pragma unroll
        for (int mk = 1; mk < 16; mk <<= 1) m = fmaxf(m, __shfl_xor(m, mk));
        const float e = expf(logit - m);
        float s = e;
#pragma unroll
        for (int mk = 1; mk < 16; mk <<= 1) s += __shfl_xor(s, mk);
        const float a = e / s;
        // token geometry
        int st0, W0;
        if (t < 10000)      { st0 = 0;     W0 = 100; }
        else if (t < 12500) { st0 = 10000; W0 = 50;  }
        else if (t < 13125) { st0 = 12500; W0 = 25;  }
        else                { st0 = 13125; W0 = 13;  }
        const int i0 = t - st0;
        const int yy = i0 / W0;
        const int xx = i0 - yy * W0;
        const float gx = (xx + 0.5f) / (float)W0;
        const float gy = (yy + 0.5f) / (float)W0;   // square levels
        // sample level
        const int lv = (u >> 2) & 3;
        const int Wv  = (lv == 0) ? 100 : (lv == 1) ? 50 : (lv == 2) ? 25 : 13;
        const int stl = (lv == 0) ? 0 : (lv == 1) ? 10000 : (lv == 2) ? 12500 : 13125;
        const unsigned int op = *(const unsigned int*)(off + tok * 256 + 2 * u);
        const float ox = bf2f((unsigned short)op);
        const float oy = bf2f((unsigned short)(op >> 16));
        const float px = (gx + ox / (float)Wv) * Wv - 0.5f;
        const float py = (gy + oy / (float)Wv) * Wv - 0.5f;
        const float fx = floorf(px), fy = floorf(py);
        const float wx1 = px - fx, wy1 = py - fy;
        const int x0 = (int)fx, y0 = (int)fy;
#pragma unroll
        for (int c = 0; c < 4; ++c) {
            const int xi = x0 + (c & 1);
            const int yi = y0 + (c >> 1);
            const float wgt = ((c & 1) ? wx1 : 1.f - wx1) * ((c >> 1) ? wy1 : 1.f - wy1);
            const bool ok = (xi >= 0) && (xi < Wv) && (yi >= 0) && (yi < Wv);
            cidx[mu][c ^ cswz] = ok ? ((stl + yi * Wv + xi) << 9) : 0;   // *512 B
            cw[mu][c ^ cswz]   = ok ? wgt * a : 0.f;
        }
    }
    __syncthreads();
    const int g = tid >> 6;                 // sample group (= wave)
    const int l = tid & 63;
    const int h = l >> 3;                   // head
    const int q = l & 7;                    // channel quad
    const char* vb = (const char*)val + ((long)b * L_TOT) * 512 + h * 64 + q * 8;
    f32x2 A01 = {0.f, 0.f}, A23 = {0.f, 0.f};
#pragma unroll
    for (int j = 0; j < 4; ++j) {
        const int mu = (j * 4 + g) * 8 + h;
        const int4   ci = *(const int4*)(&cidx[mu][0]);
        const float4 wv = *(const float4*)(&cw[mu][0]);
        const uint2 d0 = *(const uint2*)(vb + ci.x);
        const uint2 d1 = *(const uint2*)(vb + ci.y);
        const uint2 d2 = *(const uint2*)(vb + ci.z);
        const uint2 d3 = *(const uint2*)(vb + ci.w);
        A01 = fma2(bfpair(d0.x), wv.x, A01);  A23 = fma2(bfpair(d0.y), wv.x, A23);
        A01 = fma2(bfpair(d1.x), wv.y, A01);  A23 = fma2(bfpair(d1.y), wv.y, A23);
        A01 = fma2(bfpair(d2.x), wv.z, A01);  A23 = fma2(bfpair(d2.y), wv.z, A23);
        A01 = fma2(bfpair(d3.x), wv.w, A01);  A23 = fma2(bfpair(d3.y), wv.w, A23);
    }
    if (g) {
        red[g - 1][0][l] = A01.x; red[g - 1][1][l] = A01.y;
        red[g - 1][2][l] = A23.x; red[g - 1][3][l] = A23.y;
    }
    __syncthreads();
    if (g == 0) {
        float a0 = A01.x, a1 = A01.y, a2 = A23.x, a3 = A23.y;
#pragma unroll
        for (int p = 0; p < 3; ++p) {
            a0 += red[p][0][l]; a1 += red[p][1][l];
            a2 += red[p][2][l]; a3 += red[p][3][l];
        }
        ushort4 o;
        o.x = f2bf(a0); o.y = f2bf(a1); o.z = f2bf(a2); o.w = f2bf(a3);
        *(ushort4*)(attn + tok * 256 + h * 32 + q * 4) = o;
    }
}

// ---------------------------------------------------------------------------
// LayerNorm over D=256. Block = 4 waves = 4 tokens; lane = 4 channels.
// QOUT: also emit q = bf16(out) + posc (bit-exact with the old addq pass).
// ---------------------------------------------------------------------------
template<bool QOUT>
__global__ __launch_bounds__(256) void ln_k(
    const unsigned short* __restrict__ y,
    const unsigned short* __restrict__ g, const unsigned short* __restrict__ bb,
    unsigned short* __restrict__ out,
    const unsigned short* __restrict__ posc, unsigned short* __restrict__ qout,
    long nt)
{
    const int wv = threadIdx.x >> 6;
    const int lane = threadIdx.x & 63;
    const long tok = (long)blockIdx.x * 4 + wv;
    if (tok >= nt) return;
    const ushort4 v4 = *(const ushort4*)(y + tok * D + lane * 4);
    const float v0 = bf2f(v4.x), v1 = bf2f(v4.y), v2 = bf2f(v4.z), v3 = bf2f(v4.w);
    float s = v0 + v1 + v2 + v3;
#pragma unroll
    for (int m = 1; m < 64; m <<= 1) s += __shfl_xor(s, m);
    const float mean = s * (1.f / D);
    const float d0 = v0 - mean, d1 = v1 - mean, d2 = v2 - mean, d3 = v3 - mean;
    float q = d0 * d0 + d1 * d1 + d2 * d2 + d3 * d3;
#pragma unroll
    for (int m = 1; m < 64; m <<= 1) q += __shfl_xor(q, m);
    const float rstd = rsqrtf(q * (1.f / D) + 1e-5f);
    const int c0 = lane * 4;
    ushort4 o;
    o.x = f2bf(d0 * rstd * bf2f(g[c0 + 0]) + bf2f(bb[c0 + 0]));
    o.y = f2bf(d1 * rstd * bf2f(g[c0 + 1]) + bf2f(bb[c0 + 1]));
    o.z = f2bf(d2 * rstd * bf2f(g[c0 + 2]) + bf2f(bb[c0 + 2]));
    o.w = f2bf(d3 * rstd * bf2f(g[c0 + 3]) + bf2f(bb[c0 + 3]));
    *(ushort4*)(out + tok * D + c0) = o;
    if (QOUT) {
        const ushort4 p4 = *(const ushort4*)(posc + tok * D + c0);
        ushort4 qo;
        qo.x = f2bf(bf2f(o.x) + bf2f(p4.x));
        qo.y = f2bf(bf2f(o.y) + bf2f(p4.y));
        qo.z = f2bf(bf2f(o.z) + bf2f(p4.z));
        qo.w = f2bf(bf2f(o.w) + bf2f(p4.w));
        *(ushort4*)(qout + tok * D + c0) = qo;
    }
}

// ---------------------------------------------------------------------------
// Finalize: OUTPUT IS FP32.
// ---------------------------------------------------------------------------
__global__ __launch_bounds__(256) void finalize_k(
    const unsigned short* __restrict__ state, float* __restrict__ out, long osz)
{
    const long e = (long)blockIdx.x * 256 + threadIdx.x;
    const long n0 = osz - 4;
    if (e < n0) out[e] = bf2f(state[e]);
    if (e < 4) {
        const float st[4] = {0.f, 10000.f, 12500.f, 13125.f};
        out[n0 + e] = st[e];
    }
}

extern "C" void kernel_launch(void* const* d_in, const int* in_sizes, int n_in,
                              void* d_out, int out_size, void* d_ws, size_t ws_size,
                              hipStream_t stream)
{
    (void)n_in;
    const long osz = (long)out_size;
    const long nt = (osz - 4) / D;                      // total tokens
    const int nlayers = in_sizes[9] / (D * D);          // so_w: (NL, 256, 256)
    const int dff = in_sizes[19] / (nlayers * D);       // f1_w: (NL, 256, DFF)

    char* ws = (char*)d_ws;
    int* flag = (int*)ws;  ws += 256;
    unsigned short* wc = (unsigned short*)ws;           // canonical bf16 weights
    long off[25]; long acc_off = 0;
    for (int i = 8; i <= 24; ++i) { off[i] = acc_off; acc_off += in_sizes[i]; }
    ws += ((acc_off * 2 + 255) / 256) * 256;
    const size_t SZ_BF = (size_t)nt * D * 2;
    unsigned short* state     = (unsigned short*)ws;  ws += SZ_BF;  // running src
    unsigned short* val_b     = (unsigned short*)ws;  ws += SZ_BF;  // value / h lo
    unsigned short* offy_b    = (unsigned short*)ws;  ws += SZ_BF;  // offsets,y / h hi
    unsigned short* posattn_b = (unsigned short*)ws;  ws += SZ_BF;  // q, attn, ffn part
    unsigned short* aw_b      = (unsigned short*)ws;  ws += (size_t)nt * 128 * 2;
    unsigned short* hbuf = val_b;   // [nt][dff/2] spans val_b..offy_b (contiguous)

    // guarded extras: +27 MB posc (layer-invariant pos), +109 MB full-width h
    const size_t used_base = (size_t)((char*)aw_b - (char*)d_ws) + (size_t)nt * 128 * 2;
    const bool have_posc  = (ws_size >= used_base + SZ_BF);
    const bool have_hfull = (ws_size >= used_base + SZ_BF + 4 * SZ_BF);
    unsigned short* posc  = (unsigned short*)((char*)d_ws + used_base);
    unsigned short* hfull = (unsigned short*)((char*)d_ws + used_base + SZ_BF);

    probe_k<<<1, 256, 0, stream>>>((const unsigned short*)d_in[8], in_sizes[8], flag);

    // vectors/biases: plain convert
    const int vecIdx[11] = {8, 10, 12, 14, 16, 17, 18, 20, 22, 23, 24};
    for (int j = 0; j < 11; ++j) {
        const int i = vecIdx[j];
        convert_k<<<(in_sizes[i] + 255) / 256, 256, 0, stream>>>(
            d_in[i], wc + off[i], in_sizes[i], flag);
    }
    // matrices: convert + transpose to [N][K] for MFMA B-fragments
    const int matIdx[6] = {9, 11, 13, 15, 19, 21};
    const int matK[6]   = {D, D, D, D, D, dff};
    const int matN[6]   = {D, 128, D, D, dff, D};
    for (int j = 0; j < 6; ++j) {
        const int i = matIdx[j];
        convt_k<<<(in_sizes[i] + 255) / 256, 256, 0, stream>>>(
            d_in[i], wc + off[i], matK[j], matN[j], nlayers, flag);
    }

    flatten_k<<<(int)nt, 256, 0, stream>>>(
        d_in[0], d_in[2], d_in[4], d_in[6], flag, state);
    if (have_posc)
        posconst_k<<<(int)nt, 256, 0, stream>>>(
            d_in[1], d_in[3], d_in[5], d_in[7], wc + off[8], flag, posc);

    const int MB = (int)((nt + 127) / 128);
    const int LB = (int)((nt + 3) / 4);
    const long n8 = (long)nt * D / 8;
    const int AB = (int)((n8 + 255) / 256);
    const int dh = dff / 2;                     // 512: fallback FFN split

    if (have_posc)                              // layer-0 q
        addq_k<<<AB, 256, 0, stream>>>(state, posc, posattn_b, n8);

    for (int i = 0; i < nlayers; ++i) {
        if (!have_posc)
            posflat_k<<<(int)nt, 256, 0, stream>>>(
                d_in[1], d_in[3], d_in[5], d_in[7], wc + off[8], flag, state, posattn_b);
        // merged: value (cols 0-255) | offsets (256-511) | logits (512-639)
        mgemm3_k<<<dim3(5, MB), 256, 0, stream>>>(
            state, posattn_b,
            wc + off[13] + (long)i * D * D,   wc + off[14] + i * D,
            wc + off[9]  + (long)i * D * 256, wc + off[10] + i * 256,
            wc + off[11] + (long)i * D * 128, wc + off[12] + i * 128,
            val_b, offy_b, aw_b, nt);
        sample_k<<<(int)nt, 256, 0, stream>>>(offy_b, aw_b, val_b, posattn_b);
        mgemm_k<false, true><<<dim3(2, MB), 256, 0, stream>>>(  // out-proj + resid
            posattn_b, D, wc + off[15] + (long)i * D * D, D, wc + off[16] + i * D,
            state, offy_b, D, nt, D);
        ln_k<false><<<LB, 256, 0, stream>>>(offy_b, wc + off[17] + i * D,
            wc + off[18] + i * D, state, nullptr, nullptr, nt);
        if (have_hfull) {
            // full-width FFN: h = relu(x@W1+b1) [nt][1024], then one K=1024
            // GEMM with resid=state (no bf16 partial round-trip, 16 K-steps)
            mgemm_k<true, false><<<dim3(dff / 128, MB), 256, 0, stream>>>(
                state, D, wc + off[19] + (long)i * D * dff, D, wc + off[20] + i * dff,
                nullptr, hfull, dff, nt, D);
            mgemm_k<false, true><<<dim3(2, MB), 256, 0, stream>>>(
                hfull, dff, wc + off[21] + (long)i * dff * D, dff, wc + off[22] + i * D,
                state, posattn_b, D, nt, dff);
        } else {
            // fallback: FFN as 2 half-dff passes through hbuf (val_b+offy_b)
            mgemm_k<true, false><<<dim3(dh / 128, MB), 256, 0, stream>>>(
                state, D, wc + off[19] + (long)i * D * dff, D, wc + off[20] + i * dff,
                nullptr, hbuf, dh, nt, D);
            mgemm_k<false, true><<<dim3(2, MB), 256, 0, stream>>>(
                hbuf, dh, wc + off[21] + (long)i * dff * D, dff, wc + off[22] + i * D,
                state, posattn_b, D, nt, dh);
            mgemm_k<true, false><<<dim3(dh / 128, MB), 256, 0, stream>>>(
                state, D, wc + off[19] + (long)i * D * dff + (long)dh * D, D,
                wc + off[20] + i * dff + dh, nullptr, hbuf, dh, nt, D);
            mgemm_k<false, true><<<dim3(2, MB), 256, 0, stream>>>(
                hbuf, dh, wc + off[21] + (long)i * dff * D + dh, dff, nullptr,
                posattn_b, posattn_b, D, nt, dh);
        }
        // ln2; for all but last layer also emit next-layer q = bf16(out)+posc
        if (have_posc && i + 1 < nlayers)
            ln_k<true><<<LB, 256, 0, stream>>>(posattn_b, wc + off[23] + i * D,
                wc + off[24] + i * D, state, posc, posattn_b, nt);
        else
            ln_k<false><<<LB, 256, 0, stream>>>(posattn_b, wc + off[23] + i * D,
                wc + off[24] + i * D, state, nullptr, nullptr, nt);
    }

    finalize_k<<<(int)((osz - 4 + 255) / 256), 256, 0, stream>>>(
        state, (float*)d_out, osz);
}

// Round 9
// 2406.204 us; speedup vs baseline: 1.1369x; 1.0301x over previous
//
#include <hip/hip_runtime.h>

#define D 256
#define L_TOT 13294

typedef __attribute__((ext_vector_type(8))) __bf16 bf16x8;
typedef __attribute__((ext_vector_type(4))) float f32x4;
typedef __attribute__((ext_vector_type(2))) float f32x2;

__device__ __forceinline__ float bf2f(unsigned short u) {
    return __uint_as_float(((unsigned int)u) << 16);
}
__device__ __forceinline__ unsigned short f2bf(float f) {
    unsigned int u = __float_as_uint(f);
    u += 0x7FFFu + ((u >> 16) & 1u);   // round-to-nearest-even
    return (unsigned short)(u >> 16);
}
// two bf16 packed in a dword -> f32x2 {lo, hi}
__device__ __forceinline__ f32x2 bfpair(unsigned int d) {
    f32x2 r;
    r.x = __uint_as_float(d << 16);
    r.y = __uint_as_float(d & 0xFFFF0000u);
    return r;
}
__device__ __forceinline__ f32x2 fma2(f32x2 a, float w, f32x2 c) {
    return __builtin_elementwise_fma(a, (f32x2){w, w}, c);   // v_pk_fma_f32
}

// ---------------------------------------------------------------------------
// Dtype probe on level_embed: bf16 data -> ~100% sane exponents; fp32 read as
// halfwords -> ~60%. flag=1 means bf16 inputs.
// ---------------------------------------------------------------------------
__global__ void probe_k(const unsigned short* __restrict__ u, int n, int* __restrict__ flag)
{
    __shared__ int cnt;
    if (threadIdx.x == 0) cnt = 0;
    __syncthreads();
    int c = 0;
    for (int i = threadIdx.x; i < n; i += 256) {
        const int e = (u[i] >> 7) & 0xFF;
        if (e == 0 || (e >= 96 && e <= 150)) ++c;
    }
    atomicAdd(&cnt, c);
    __syncthreads();
    if (threadIdx.x == 0) *flag = (cnt * 10 > n * 9) ? 1 : 0;
}

__global__ __launch_bounds__(256) void convert_k(
    const void* __restrict__ src, unsigned short* __restrict__ dst, int n,
    const int* __restrict__ flag)
{
    const int i = blockIdx.x * 256 + threadIdx.x;
    if (i >= n) return;
    if (*flag) dst[i] = ((const unsigned short*)src)[i];
    else       dst[i] = f2bf(((const float*)src)[i]);
}

// Convert + transpose: src (L,K,N) -> dst (L,N,K) bf16.
__global__ __launch_bounds__(256) void convt_k(
    const void* __restrict__ src, unsigned short* __restrict__ dst,
    int K, int N, int L, const int* __restrict__ flag)
{
    const long e = (long)blockIdx.x * 256 + threadIdx.x;
    const long tot = (long)L * K * N;
    if (e >= tot) return;
    const int per = K * N;
    const int li = (int)(e / per);
    const int r  = (int)(e - (long)li * per);
    const int n  = r / K;
    const int k  = r - n * K;
    const long s = (long)li * per + (long)k * N + n;
    dst[e] = (*flag) ? ((const unsigned short*)src)[s]
                     : f2bf(((const float*)src)[s]);
}

// ---------------------------------------------------------------------------
// Flatten (B,D,H,W) src inputs -> state bf16 (tok,D).
// ---------------------------------------------------------------------------
__global__ __launch_bounds__(256) void flatten_k(
    const void* __restrict__ s0, const void* __restrict__ s1,
    const void* __restrict__ s2, const void* __restrict__ s3,
    const int* __restrict__ flag, unsigned short* __restrict__ state)
{
    const long e = (long)blockIdx.x * 256 + threadIdx.x;
    const int d = (int)(e & 255);
    const long tok = e >> 8;
    const int b = (int)(tok / L_TOT);
    const int t = (int)(tok - (long)b * L_TOT);
    const void *sp;
    int hw, idx;
    if (t < 10000)      { sp = s0; hw = 10000; idx = t;          }
    else if (t < 12500) { sp = s1; hw = 2500;  idx = t - 10000;  }
    else if (t < 13125) { sp = s2; hw = 625;   idx = t - 12500;  }
    else                { sp = s3; hw = 169;   idx = t - 13125;  }
    const long a = ((long)b * D + d) * hw + idx;
    state[e] = (*flag) ? ((const unsigned short*)sp)[a]
                       : f2bf(((const float*)sp)[a]);
}

// Layer-invariant pos precompute: posc = pos_input + level_embed (bf16).
__global__ __launch_bounds__(256) void posconst_k(
    const void* __restrict__ p0, const void* __restrict__ p1,
    const void* __restrict__ p2, const void* __restrict__ p3,
    const unsigned short* __restrict__ lev, const int* __restrict__ flag,
    unsigned short* __restrict__ posc)
{
    const long e = (long)blockIdx.x * 256 + threadIdx.x;
    const int d = (int)(e & 255);
    const long tok = e >> 8;
    const int b = (int)(tok / L_TOT);
    const int t = (int)(tok - (long)b * L_TOT);
    const void *pp;
    int hw, idx, l;
    if (t < 10000)      { pp = p0; hw = 10000; idx = t;          l = 0; }
    else if (t < 12500) { pp = p1; hw = 2500;  idx = t - 10000;  l = 1; }
    else if (t < 13125) { pp = p2; hw = 625;   idx = t - 12500;  l = 2; }
    else                { pp = p3; hw = 169;   idx = t - 13125;  l = 3; }
    const long a = ((long)b * D + d) * hw + idx;
    const float pv = (*flag) ? bf2f(((const unsigned short*)pp)[a])
                             : ((const float*)pp)[a];
    posc[e] = f2bf(pv + bf2f(lev[l * D + d]));
}

// q = x + posc, fully coalesced uint4 (8 bf16/thread). (layer-0 only)
__global__ __launch_bounds__(256) void addq_k(
    const unsigned short* __restrict__ x, const unsigned short* __restrict__ p,
    unsigned short* __restrict__ q, long n8)
{
    const long e = (long)blockIdx.x * 256 + threadIdx.x;
    if (e >= n8) return;
    const uint4 xv = ((const uint4*)x)[e];
    const uint4 pv = ((const uint4*)p)[e];
    uint4 o;
#define ADDPK(a, b) ({ const f32x2 fa = bfpair(a), fb = bfpair(b); \
        (unsigned int)f2bf(fb.x + fa.x) | ((unsigned int)f2bf(fb.y + fa.y) << 16); })
    o.x = ADDPK(xv.x, pv.x); o.y = ADDPK(xv.y, pv.y);
    o.z = ADDPK(xv.z, pv.z); o.w = ADDPK(xv.w, pv.w);
#undef ADDPK
    ((uint4*)q)[e] = o;
}

// Fallback (tight workspace): per-layer q = x + pos_input + level_embed.
__global__ __launch_bounds__(256) void posflat_k(
    const void* __restrict__ p0, const void* __restrict__ p1,
    const void* __restrict__ p2, const void* __restrict__ p3,
    const unsigned short* __restrict__ lev, const int* __restrict__ flag,
    const unsigned short* __restrict__ x, unsigned short* __restrict__ q)
{
    const long e = (long)blockIdx.x * 256 + threadIdx.x;
    const int d = (int)(e & 255);
    const long tok = e >> 8;
    const int b = (int)(tok / L_TOT);
    const int t = (int)(tok - (long)b * L_TOT);
    const void *pp;
    int hw, idx, l;
    if (t < 10000)      { pp = p0; hw = 10000; idx = t;          l = 0; }
    else if (t < 12500) { pp = p1; hw = 2500;  idx = t - 10000;  l = 1; }
    else if (t < 13125) { pp = p2; hw = 625;   idx = t - 12500;  l = 2; }
    else                { pp = p3; hw = 169;   idx = t - 13125;  l = 3; }
    const long a = ((long)b * D + d) * hw + idx;
    const float pv = (*flag) ? bf2f(((const unsigned short*)pp)[a])
                             : ((const float*)pp)[a];
    q[e] = f2bf(pv + bf2f(lev[l * D + d]) + bf2f(x[e]));
}

// ---------------------------------------------------------------------------
// MFMA GEMM core, single-buffered m97 structure, BK=64 (R7: BK=32 dbuf
// regressed; R3: BK=64 dbuf cost occupancy; this is the measured optimum).
// Tile 128x128, 4 waves (2x2). OPERANDS SWAPPED: acc = mfma(bfr, af, acc) ->
// lane holds row (l&15), 4 consecutive cols (l>>4)*4+r -> ushort4 epilogue.
// LDS XOR-swizzle in 16B groups (G4); global source pre-swizzled (rule #21).
// ---------------------------------------------------------------------------
template<bool RELU, bool RESID>
__device__ __forceinline__ void gemm_core(
    const unsigned short* __restrict__ A, int ldA,
    const unsigned short* __restrict__ Bt, int ldB,
    const unsigned short* __restrict__ bias,
    const unsigned short* resid,          // may alias out
    unsigned short* out, int ldO,
    long M, int K, int col0, long row0,
    unsigned short* As, unsigned short* Bs)
{
    const int tid = threadIdx.x;
    const int l  = tid & 63;
    const int w  = tid >> 6;
    const int wm = w >> 1, wn = w & 1;

    f32x4 acc[4][4];
#pragma unroll
    for (int i = 0; i < 4; ++i)
#pragma unroll
        for (int j = 0; j < 4; ++j) acc[i][j] = (f32x4){0.f, 0.f, 0.f, 0.f};

    const int sr = tid >> 3;
    const int sg = tid & 7;

    for (int k0 = 0; k0 < K; k0 += 64) {
#pragma unroll
        for (int i = 0; i < 4; ++i) {
            const int r = i * 32 + sr;
            long arow = row0 + r; if (arow >= M) arow = M - 1;   // clamp tail
            const int ke = k0 + ((sg ^ (r & 7)) << 3);           // pre-swizzled src
            const unsigned short* ga = A  + arow * (long)ldA + ke;
            const unsigned short* gb = Bt + (long)(col0 + r) * ldB + ke;
            __builtin_amdgcn_global_load_lds(
                (const __attribute__((address_space(1))) void*)ga,
                (__attribute__((address_space(3))) void*)(As + i * 2048 + w * 512),
                16, 0, 0);
            __builtin_amdgcn_global_load_lds(
                (const __attribute__((address_space(1))) void*)gb,
                (__attribute__((address_space(3))) void*)(Bs + i * 2048 + w * 512),
                16, 0, 0);
        }
        __syncthreads();    // drains vmcnt, tiles ready
#pragma unroll
        for (int ks = 0; ks < 2; ++ks) {
            const int cc  = ks * 4 + (l >> 4);
            const int swz = ((cc ^ (l & 7)) << 4);
            bf16x8 af[4], bfr[4];
#pragma unroll
            for (int mi = 0; mi < 4; ++mi) {
                const int ar = wm * 64 + mi * 16 + (l & 15);
                af[mi] = *(const bf16x8*)((const char*)As + ar * 128 + swz);
            }
#pragma unroll
            for (int ni = 0; ni < 4; ++ni) {
                const int br = wn * 64 + ni * 16 + (l & 15);
                bfr[ni] = *(const bf16x8*)((const char*)Bs + br * 128 + swz);
            }
#pragma unroll
            for (int mi = 0; mi < 4; ++mi)
#pragma unroll
                for (int ni = 0; ni < 4; ++ni)
                    acc[mi][ni] = __builtin_amdgcn_mfma_f32_16x16x32_bf16(
                        bfr[ni], af[mi], acc[mi][ni], 0, 0, 0);   // SWAPPED -> C^T frag
        }
        __syncthreads();    // compute done before next stage overwrites
    }

    // epilogue: lane holds row (l&15), 4 consecutive cols (l>>4)*4+r
#pragma unroll
    for (int mi = 0; mi < 4; ++mi) {
        const long rr = row0 + wm * 64 + mi * 16 + (l & 15);
        if (rr >= M) continue;
#pragma unroll
        for (int ni = 0; ni < 4; ++ni) {
            const int col = col0 + wn * 64 + ni * 16 + (l >> 4) * 4;
            f32x4 v = acc[mi][ni];
            if (bias) {
                const ushort4 b4 = *(const ushort4*)(bias + col);
                v[0] += bf2f(b4.x); v[1] += bf2f(b4.y);
                v[2] += bf2f(b4.z); v[3] += bf2f(b4.w);
            }
            if (RELU) {
                v[0] = fmaxf(v[0], 0.f); v[1] = fmaxf(v[1], 0.f);
                v[2] = fmaxf(v[2], 0.f); v[3] = fmaxf(v[3], 0.f);
            }
            if (RESID) {
                const ushort4 r4 = *(const ushort4*)(resid + rr * (long)ldO + col);
                v[0] += bf2f(r4.x); v[1] += bf2f(r4.y);
                v[2] += bf2f(r4.z); v[3] += bf2f(r4.w);
            }
            ushort4 o;
            o.x = f2bf(v[0]); o.y = f2bf(v[1]); o.z = f2bf(v[2]); o.w = f2bf(v[3]);
            *(ushort4*)(out + rr * (long)ldO + col) = o;
        }
    }
}

template<bool RELU, bool RESID>
__global__ __launch_bounds__(256, 3) void mgemm_k(
    const unsigned short* __restrict__ A, int ldA,
    const unsigned short* __restrict__ Bt, int ldB,
    const unsigned short* __restrict__ bias,
    const unsigned short* resid,
    unsigned short* out, int ldOut,
    long M, int K)
{
    __shared__ unsigned short As[8192];
    __shared__ unsigned short Bs[8192];
    gemm_core<RELU, RESID>(A, ldA, Bt, ldB, bias, resid, out, ldOut,
                           M, K, blockIdx.x * 128, (long)blockIdx.y * 128, As, Bs);
}

// Merged value + sampling-offsets + attn-logits (one dispatch; segment select
// is block-uniform). grid = dim3(5, MB): cols 0-1 value, 2-3 offsets, 4 logits.
__global__ __launch_bounds__(256, 3) void mgemm3_k(
    const unsigned short* __restrict__ state, const unsigned short* __restrict__ q,
    const unsigned short* __restrict__ Wv,  const unsigned short* __restrict__ bv,
    const unsigned short* __restrict__ Wso, const unsigned short* __restrict__ bso,
    const unsigned short* __restrict__ Waw, const unsigned short* __restrict__ baw,
    unsigned short* valo, unsigned short* offo, unsigned short* awo, long M)
{
    __shared__ unsigned short As[8192];
    __shared__ unsigned short Bs[8192];
    const int cx = blockIdx.x * 128;
    const long row0 = (long)blockIdx.y * 128;
    if (cx < 256)
        gemm_core<false, false>(state, D, Wv, D, bv, nullptr, valo, D,
                                M, D, cx, row0, As, Bs);
    else if (cx < 512)
        gemm_core<false, false>(q, D, Wso, D, bso, nullptr, offo, D,
                                M, D, cx - 256, row0, As, Bs);
    else
        gemm_core<false, false>(q, D, Waw, D, baw, nullptr, awo, 128,
                                M, D, 0, row0, As, Bs);
}

// ---------------------------------------------------------------------------
// GEMM + residual + LayerNorm fused (out = LN(resid + A@B + bias), optional
// q = bf16(out)+posc). Tile 64 rows x 256 cols (FULL token row per block ->
// LN feasible); 4 waves each own a 64x64 quadrant (per-wave work identical to
// gemm_core: acc[4][4], 32 MFMA/K-step). LDS: A 8KB + B 32KB + red 2KB = 42KB
// -> still 3 blocks/CU. NUMERICS: y is rounded to bf16 BEFORE the LN stats,
// bit-identical to the old separate ln_k pass over a bf16 y buffer.
// resid/outp may alias (each thread reads its own cells before writing; waves
// cover disjoint cols of the block's rows).
// ---------------------------------------------------------------------------
template<bool QOUT>
__global__ __launch_bounds__(256, 3) void mgemmln_k(
    const unsigned short* __restrict__ A, int ldA,
    const unsigned short* __restrict__ Bt, int ldB,
    const unsigned short* __restrict__ bias,
    const unsigned short* resid,
    const unsigned short* __restrict__ gamma,
    const unsigned short* __restrict__ beta,
    unsigned short* outp,
    const unsigned short* __restrict__ posc,
    unsigned short* __restrict__ qout,
    long M, int K)
{
    __shared__ unsigned short As[64 * 64];      // 8 KB
    __shared__ unsigned short Bs[256 * 64];     // 32 KB
    __shared__ float red[2][4][4][16];          // [sum|sq][wave][mi][row16]
    const int tid = threadIdx.x;
    const int l = tid & 63;
    const int w = tid >> 6;
    const long row0 = (long)blockIdx.x * 64;

    f32x4 acc[4][4];
#pragma unroll
    for (int i = 0; i < 4; ++i)
#pragma unroll
        for (int j = 0; j < 4; ++j) acc[i][j] = (f32x4){0.f, 0.f, 0.f, 0.f};

    for (int k0 = 0; k0 < K; k0 += 64) {
#pragma unroll
        for (int i = 0; i < 10; ++i) {           // 2 rounds A, 8 rounds B
            const int c = i * 256 + tid;
            const unsigned short* gsrc;
            unsigned short* ldst;
            if (i < 2) {
                const int r = c >> 3, grp = c & 7;
                long ar = row0 + r; if (ar >= M) ar = M - 1;
                gsrc = A + ar * (long)ldA + (k0 + ((grp ^ (r & 7)) << 3));
                ldst = As + (c << 3);
            } else {
                const int r = (c >> 3) - 64, grp = c & 7;
                gsrc = Bt + (long)r * ldB + (k0 + ((grp ^ (r & 7)) << 3));
                ldst = Bs + ((c - 512) << 3);
            }
            __builtin_amdgcn_global_load_lds(
                (const __attribute__((address_space(1))) void*)gsrc,
                (__attribute__((address_space(3))) void*)ldst, 16, 0, 0);
        }
        __syncthreads();
#pragma unroll
        for (int ks = 0; ks < 2; ++ks) {
            const int cc = ks * 4 + (l >> 4);
            bf16x8 af[4], bfr[4];
#pragma unroll
            for (int mi = 0; mi < 4; ++mi) {
                const int ar = mi * 16 + (l & 15);
                af[mi] = *(const bf16x8*)((const char*)As + ar * 128 + ((cc ^ (ar & 7)) << 4));
            }
#pragma unroll
            for (int ni = 0; ni < 4; ++ni) {
                const int br = w * 64 + ni * 16 + (l & 15);
                bfr[ni] = *(const bf16x8*)((const char*)Bs + br * 128 + ((cc ^ (br & 7)) << 4));
            }
#pragma unroll
            for (int mi = 0; mi < 4; ++mi)
#pragma unroll
                for (int ni = 0; ni < 4; ++ni)
                    acc[mi][ni] = __builtin_amdgcn_mfma_f32_16x16x32_bf16(
                        bfr[ni], af[mi], acc[mi][ni], 0, 0, 0);
        }
        __syncthreads();
    }

    // ---- epilogue: y = bf16(gemm + bias + resid); LN stats over 256 cols ---
#pragma unroll
    for (int mi = 0; mi < 4; ++mi) {
        const long rr = row0 + mi * 16 + (l & 15);
        const long rrc = (rr < M) ? rr : (M - 1);
#pragma unroll
        for (int ni = 0; ni < 4; ++ni) {
            const int col = w * 64 + ni * 16 + (l >> 4) * 4;
            const ushort4 b4 = *(const ushort4*)(bias + col);
            const ushort4 r4 = *(const ushort4*)(resid + rrc * D + col);
            acc[mi][ni][0] = bf2f(f2bf(acc[mi][ni][0] + bf2f(b4.x) + bf2f(r4.x)));
            acc[mi][ni][1] = bf2f(f2bf(acc[mi][ni][1] + bf2f(b4.y) + bf2f(r4.y)));
            acc[mi][ni][2] = bf2f(f2bf(acc[mi][ni][2] + bf2f(b4.z) + bf2f(r4.z)));
            acc[mi][ni][3] = bf2f(f2bf(acc[mi][ni][3] + bf2f(b4.w) + bf2f(r4.w)));
        }
    }
#pragma unroll
    for (int mi = 0; mi < 4; ++mi) {
        float s = 0.f, qq = 0.f;
#pragma unroll
        for (int ni = 0; ni < 4; ++ni)
#pragma unroll
            for (int r = 0; r < 4; ++r) {
                const float v = acc[mi][ni][r];
                s += v; qq += v * v;
            }
        s += __shfl_xor(s, 16);  s += __shfl_xor(s, 32);
        qq += __shfl_xor(qq, 16); qq += __shfl_xor(qq, 32);
        if (l < 16) { red[0][w][mi][l] = s; red[1][w][mi][l] = qq; }
    }
    __syncthreads();
    float mean[4], rstd[4];
#pragma unroll
    for (int mi = 0; mi < 4; ++mi) {
        const int r16 = l & 15;
        const float s = red[0][0][mi][r16] + red[0][1][mi][r16]
                      + red[0][2][mi][r16] + red[0][3][mi][r16];
        const float qq = red[1][0][mi][r16] + red[1][1][mi][r16]
                       + red[1][2][mi][r16] + red[1][3][mi][r16];
        const float mn = s * (1.f / D);
        const float var = qq * (1.f / D) - mn * mn;
        mean[mi] = mn;
        rstd[mi] = rsqrtf(var + 1e-5f);
    }
#pragma unroll
    for (int mi = 0; mi < 4; ++mi) {
        const long rr = row0 + mi * 16 + (l & 15);
        if (rr >= M) continue;
#pragma unroll
        for (int ni = 0; ni < 4; ++ni) {
            const int col = w * 64 + ni * 16 + (l >> 4) * 4;
            const ushort4 g4 = *(const ushort4*)(gamma + col);
            const ushort4 e4 = *(const ushort4*)(beta + col);
            ushort4 o;
            o.x = f2bf((acc[mi][ni][0] - mean[mi]) * rstd[mi] * bf2f(g4.x) + bf2f(e4.x));
            o.y = f2bf((acc[mi][ni][1] - mean[mi]) * rstd[mi] * bf2f(g4.y) + bf2f(e4.y));
            o.z = f2bf((acc[mi][ni][2] - mean[mi]) * rstd[mi] * bf2f(g4.z) + bf2f(e4.z));
            o.w = f2bf((acc[mi][ni][3] - mean[mi]) * rstd[mi] * bf2f(g4.w) + bf2f(e4.w));
            *(ushort4*)(outp + rr * D + col) = o;
            if (QOUT) {
                const ushort4 p4 = *(const ushort4*)(posc + rr * D + col);
                ushort4 qo;
                qo.x = f2bf(bf2f(o.x) + bf2f(p4.x));
                qo.y = f2bf(bf2f(o.y) + bf2f(p4.y));
                qo.z = f2bf(bf2f(o.z) + bf2f(p4.z));
                qo.w = f2bf(bf2f(o.w) + bf2f(p4.w));
                *(ushort4*)(qout + rr * D + col) = qo;
            }
        }
    }
}

// ---------------------------------------------------------------------------
// Deformable sampling. One block per token (R7: XCD swizzle reverted — kernel
// is VALU-bound). Prep tables at [mu=lp*8+h][c ^ (lp&3)] (4-way write
// conflict, pair-preserving XOR). Gather: int4/float4 table reads, 4
// unconditional uint2 loads/j + packed f32x2 fma. [3][4][64] LDS reduce.
// ---------------------------------------------------------------------------
__global__ __launch_bounds__(256) void sample_k(
    const unsigned short* __restrict__ off, const unsigned short* __restrict__ aw,
    const unsigned short* __restrict__ val, unsigned short* __restrict__ attn)
{
    __shared__ __align__(16) int   cidx[128][4];   // byte offsets into val rows
    __shared__ __align__(16) float cw[128][4];
    __shared__ float red[3][4][64];
    const long tok = blockIdx.x;
    const int tid = threadIdx.x;
    const int b = (int)(tok / L_TOT);
    const int t = (int)(tok - (long)b * L_TOT);

    if (tid < 128) {
        const int u = tid;                       // u = h*16 + lp
        const int lp = u & 15;
        const int mu = lp * 8 + (u >> 4);        // [lp*8+h]
        const int cswz = lp & 3;                 // pair-preserving bank swizzle
        // softmax over the 16 samples of this head (16-lane shfl groups)
        const float logit = bf2f(aw[tok * 128 + u]);
        float m = logit;
#pragma unroll
        for (int mk = 1; mk < 16; mk <<= 1) m = fmaxf(m, __shfl_xor(m, mk));
        const float e = expf(logit - m);
        float s = e;
#pragma unroll
        for (int mk = 1; mk < 16; mk <<= 1) s += __shfl_xor(s, mk);
        const float a = e / s;
        // token geometry
        int st0, W0;
        if (t < 10000)      { st0 = 0;     W0 = 100; }
        else if (t < 12500) { st0 = 10000; W0 = 50;  }
        else if (t < 13125) { st0 = 12500; W0 = 25;  }
        else                { st0 = 13125; W0 = 13;  }
        const int i0 = t - st0;
        const int yy = i0 / W0;
        const int xx = i0 - yy * W0;
        const float gx = (xx + 0.5f) / (float)W0;
        const float gy = (yy + 0.5f) / (float)W0;   // square levels
        // sample level
        const int lv = (u >> 2) & 3;
        const int Wv  = (lv == 0) ? 100 : (lv == 1) ? 50 : (lv == 2) ? 25 : 13;
        const int stl = (lv == 0) ? 0 : (lv == 1) ? 10000 : (lv == 2) ? 12500 : 13125;
        const unsigned int op = *(const unsigned int*)(off + tok * 256 + 2 * u);
        const float ox = bf2f((unsigned short)op);
        const float oy = bf2f((unsigned short)(op >> 16));
        const float px = (gx + ox / (float)Wv) * Wv - 0.5f;
        const float py = (gy + oy / (float)Wv) * Wv - 0.5f;
        const float fx = floorf(px), fy = floorf(py);
        const float wx1 = px - fx, wy1 = py - fy;
        const int x0 = (int)fx, y0 = (int)fy;
#pragma unroll
        for (int c = 0; c < 4; ++c) {
            const int xi = x0 + (c & 1);
            const int yi = y0 + (c >> 1);
            const float wgt = ((c & 1) ? wx1 : 1.f - wx1) * ((c >> 1) ? wy1 : 1.f - wy1);
            const bool ok = (xi >= 0) && (xi < Wv) && (yi >= 0) && (yi < Wv);
            cidx[mu][c ^ cswz] = ok ? ((stl + yi * Wv + xi) << 9) : 0;   // *512 B
            cw[mu][c ^ cswz]   = ok ? wgt * a : 0.f;
        }
    }
    __syncthreads();
    const int g = tid >> 6;                 // sample group (= wave)
    const int l = tid & 63;
    const int h = l >> 3;                   // head
    const int q = l & 7;                    // channel quad
    const char* vb = (const char*)val + ((long)b * L_TOT) * 512 + h * 64 + q * 8;
    f32x2 A01 = {0.f, 0.f}, A23 = {0.f, 0.f};
#pragma unroll
    for (int j = 0; j < 4; ++j) {
        const int mu = (j * 4 + g) * 8 + h;
        const int4   ci = *(const int4*)(&cidx[mu][0]);
        const float4 wv = *(const float4*)(&cw[mu][0]);
        const uint2 d0 = *(const uint2*)(vb + ci.x);
        const uint2 d1 = *(const uint2*)(vb + ci.y);
        const uint2 d2 = *(const uint2*)(vb + ci.z);
        const uint2 d3 = *(const uint2*)(vb + ci.w);
        A01 = fma2(bfpair(d0.x), wv.x, A01);  A23 = fma2(bfpair(d0.y), wv.x, A23);
        A01 = fma2(bfpair(d1.x), wv.y, A01);  A23 = fma2(bfpair(d1.y), wv.y, A23);
        A01 = fma2(bfpair(d2.x), wv.z, A01);  A23 = fma2(bfpair(d2.y), wv.z, A23);
        A01 = fma2(bfpair(d3.x), wv.w, A01);  A23 = fma2(bfpair(d3.y), wv.w, A23);
    }
    if (g) {
        red[g - 1][0][l] = A01.x; red[g - 1][1][l] = A01.y;
        red[g - 1][2][l] = A23.x; red[g - 1][3][l] = A23.y;
    }
    __syncthreads();
    if (g == 0) {
        float a0 = A01.x, a1 = A01.y, a2 = A23.x, a3 = A23.y;
#pragma unroll
        for (int p = 0; p < 3; ++p) {
            a0 += red[p][0][l]; a1 += red[p][1][l];
            a2 += red[p][2][l]; a3 += red[p][3][l];
        }
        ushort4 o;
        o.x = f2bf(a0); o.y = f2bf(a1); o.z = f2bf(a2); o.w = f2bf(a3);
        *(ushort4*)(attn + tok * 256 + h * 32 + q * 4) = o;
    }
}

// ---------------------------------------------------------------------------
// LayerNorm over D=256 (fallback path only). Block = 4 waves = 4 tokens.
// ---------------------------------------------------------------------------
template<bool QOUT>
__global__ __launch_bounds__(256) void ln_k(
    const unsigned short* __restrict__ y,
    const unsigned short* __restrict__ g, const unsigned short* __restrict__ bb,
    unsigned short* __restrict__ out,
    const unsigned short* __restrict__ posc, unsigned short* __restrict__ qout,
    long nt)
{
    const int wv = threadIdx.x >> 6;
    const int lane = threadIdx.x & 63;
    const long tok = (long)blockIdx.x * 4 + wv;
    if (tok >= nt) return;
    const ushort4 v4 = *(const ushort4*)(y + tok * D + lane * 4);
    const float v0 = bf2f(v4.x), v1 = bf2f(v4.y), v2 = bf2f(v4.z), v3 = bf2f(v4.w);
    float s = v0 + v1 + v2 + v3;
#pragma unroll
    for (int m = 1; m < 64; m <<= 1) s += __shfl_xor(s, m);
    const float mean = s * (1.f / D);
    const float d0 = v0 - mean, d1 = v1 - mean, d2 = v2 - mean, d3 = v3 - mean;
    float q = d0 * d0 + d1 * d1 + d2 * d2 + d3 * d3;
#pragma unroll
    for (int m = 1; m < 64; m <<= 1) q += __shfl_xor(q, m);
    const float rstd = rsqrtf(q * (1.f / D) + 1e-5f);
    const int c0 = lane * 4;
    ushort4 o;
    o.x = f2bf(d0 * rstd * bf2f(g[c0 + 0]) + bf2f(bb[c0 + 0]));
    o.y = f2bf(d1 * rstd * bf2f(g[c0 + 1]) + bf2f(bb[c0 + 1]));
    o.z = f2bf(d2 * rstd * bf2f(g[c0 + 2]) + bf2f(bb[c0 + 2]));
    o.w = f2bf(d3 * rstd * bf2f(g[c0 + 3]) + bf2f(bb[c0 + 3]));
    *(ushort4*)(out + tok * D + c0) = o;
    if (QOUT) {
        const ushort4 p4 = *(const ushort4*)(posc + tok * D + c0);
        ushort4 qo;
        qo.x = f2bf(bf2f(o.x) + bf2f(p4.x));
        qo.y = f2bf(bf2f(o.y) + bf2f(p4.y));
        qo.z = f2bf(bf2f(o.z) + bf2f(p4.z));
        qo.w = f2bf(bf2f(o.w) + bf2f(p4.w));
        *(ushort4*)(qout + tok * D + c0) = qo;
    }
}

// ---------------------------------------------------------------------------
// Finalize: OUTPUT IS FP32.
// ---------------------------------------------------------------------------
__global__ __launch_bounds__(256) void finalize_k(
    const unsigned short* __restrict__ state, float* __restrict__ out, long osz)
{
    const long e = (long)blockIdx.x * 256 + threadIdx.x;
    const long n0 = osz - 4;
    if (e < n0) out[e] = bf2f(state[e]);
    if (e < 4) {
        const float st[4] = {0.f, 10000.f, 12500.f, 13125.f};
        out[n0 + e] = st[e];
    }
}

extern "C" void kernel_launch(void* const* d_in, const int* in_sizes, int n_in,
                              void* d_out, int out_size, void* d_ws, size_t ws_size,
                              hipStream_t stream)
{
    (void)n_in;
    const long osz = (long)out_size;
    const long nt = (osz - 4) / D;                      // total tokens
    const int nlayers = in_sizes[9] / (D * D);          // so_w: (NL, 256, 256)
    const int dff = in_sizes[19] / (nlayers * D);       // f1_w: (NL, 256, DFF)

    char* ws = (char*)d_ws;
    int* flag = (int*)ws;  ws += 256;
    unsigned short* wc = (unsigned short*)ws;           // canonical bf16 weights
    long off[25]; long acc_off = 0;
    for (int i = 8; i <= 24; ++i) { off[i] = acc_off; acc_off += in_sizes[i]; }
    ws += ((acc_off * 2 + 255) / 256) * 256;
    const size_t SZ_BF = (size_t)nt * D * 2;
    unsigned short* state     = (unsigned short*)ws;  ws += SZ_BF;  // running src
    unsigned short* val_b     = (unsigned short*)ws;  ws += SZ_BF;  // value / h lo
    unsigned short* offy_b    = (unsigned short*)ws;  ws += SZ_BF;  // offsets,y / h hi
    unsigned short* posattn_b = (unsigned short*)ws;  ws += SZ_BF;  // q, attn
    unsigned short* aw_b      = (unsigned short*)ws;  ws += (size_t)nt * 128 * 2;
    unsigned short* hbuf = val_b;   // [nt][dff/2] spans val_b..offy_b (contiguous)

    // guarded extras: +27 MB posc (layer-invariant pos), +109 MB full-width h
    const size_t used_base = (size_t)((char*)aw_b - (char*)d_ws) + (size_t)nt * 128 * 2;
    const bool have_posc  = (ws_size >= used_base + SZ_BF);
    const bool have_hfull = (ws_size >= used_base + SZ_BF + 4 * SZ_BF);
    unsigned short* posc  = (unsigned short*)((char*)d_ws + used_base);
    unsigned short* hfull = (unsigned short*)((char*)d_ws + used_base + SZ_BF);

    probe_k<<<1, 256, 0, stream>>>((const unsigned short*)d_in[8], in_sizes[8], flag);

    // vectors/biases: plain convert
    const int vecIdx[11] = {8, 10, 12, 14, 16, 17, 18, 20, 22, 23, 24};
    for (int j = 0; j < 11; ++j) {
        const int i = vecIdx[j];
        convert_k<<<(in_sizes[i] + 255) / 256, 256, 0, stream>>>(
            d_in[i], wc + off[i], in_sizes[i], flag);
    }
    // matrices: convert + transpose to [N][K] for MFMA B-fragments
    const int matIdx[6] = {9, 11, 13, 15, 19, 21};
    const int matK[6]   = {D, D, D, D, D, dff};
    const int matN[6]   = {D, 128, D, D, dff, D};
    for (int j = 0; j < 6; ++j) {
        const int i = matIdx[j];
        convt_k<<<(in_sizes[i] + 255) / 256, 256, 0, stream>>>(
            d_in[i], wc + off[i], matK[j], matN[j], nlayers, flag);
    }

    flatten_k<<<(int)nt, 256, 0, stream>>>(
        d_in[0], d_in[2], d_in[4], d_in[6], flag, state);
    if (have_posc)
        posconst_k<<<(int)nt, 256, 0, stream>>>(
            d_in[1], d_in[3], d_in[5], d_in[7], wc + off[8], flag, posc);

    const int MB = (int)((nt + 127) / 128);
    const int FB = (int)((nt + 63) / 64);
    const int LB = (int)((nt + 3) / 4);
    const long n8 = (long)nt * D / 8;
    const int AB = (int)((n8 + 255) / 256);
    const int dh = dff / 2;                     // 512: fallback FFN split

    if (have_posc)                              // layer-0 q
        addq_k<<<AB, 256, 0, stream>>>(state, posc, posattn_b, n8);

    for (int i = 0; i < nlayers; ++i) {
        if (!have_posc)
            posflat_k<<<(int)nt, 256, 0, stream>>>(
                d_in[1], d_in[3], d_in[5], d_in[7], wc + off[8], flag, state, posattn_b);
        // merged: value (cols 0-255) | offsets (256-511) | logits (512-639)
        mgemm3_k<<<dim3(5, MB), 256, 0, stream>>>(
            state, posattn_b,
            wc + off[13] + (long)i * D * D,   wc + off[14] + i * D,
            wc + off[9]  + (long)i * D * 256, wc + off[10] + i * 256,
            wc + off[11] + (long)i * D * 128, wc + off[12] + i * 128,
            val_b, offy_b, aw_b, nt);
        sample_k<<<(int)nt, 256, 0, stream>>>(offy_b, aw_b, val_b, posattn_b);
        if (have_hfull) {
            // out-proj + resid + LN1 fused -> state (in place)
            mgemmln_k<false><<<FB, 256, 0, stream>>>(
                posattn_b, D, wc + off[15] + (long)i * D * D, D, wc + off[16] + i * D,
                state, wc + off[17] + i * D, wc + off[18] + i * D, state,
                nullptr, nullptr, nt, D);
            // full-width FFN: h = relu(x@W1+b1) [nt][1024]
            mgemm_k<true, false><<<dim3(dff / 128, MB), 256, 0, stream>>>(
                state, D, wc + off[19] + (long)i * D * dff, D, wc + off[20] + i * dff,
                nullptr, hfull, dff, nt, D);
            // f2 (K=1024) + resid + LN2 (+ next-layer q) fused -> state
            if (have_posc && i + 1 < nlayers)
                mgemmln_k<true><<<FB, 256, 0, stream>>>(
                    hfull, dff, wc + off[21] + (long)i * dff * D, dff,
                    wc + off[22] + i * D, state,
                    wc + off[23] + i * D, wc + off[24] + i * D, state,
                    posc, posattn_b, nt, dff);
            else
                mgemmln_k<false><<<FB, 256, 0, stream>>>(
                    hfull, dff, wc + off[21] + (long)i * dff * D, dff,
                    wc + off[22] + i * D, state,
                    wc + off[23] + i * D, wc + off[24] + i * D, state,
                    nullptr, nullptr, nt, dff);
        } else {
            mgemm_k<false, true><<<dim3(2, MB), 256, 0, stream>>>(  // out-proj + resid
                posattn_b, D, wc + off[15] + (long)i * D * D, D, wc + off[16] + i * D,
                state, offy_b, D, nt, D);
            ln_k<false><<<LB, 256, 0, stream>>>(offy_b, wc + off[17] + i * D,
                wc + off[18] + i * D, state, nullptr, nullptr, nt);
            // fallback: FFN as 2 half-dff passes through hbuf (val_b+offy_b)
            mgemm_k<true, false><<<dim3(dh / 128, MB), 256, 0, stream>>>(
                state, D, wc + off[19] + (long)i * D * dff, D, wc + off[20] + i * dff,
                nullptr, hbuf, dh, nt, D);
            mgemm_k<false, true><<<dim3(2, MB), 256, 0, stream>>>(
                hbuf, dh, wc + off[21] + (long)i * dff * D, dff, wc + off[22] + i * D,
                state, posattn_b, D, nt, dh);
            mgemm_k<true, false><<<dim3(dh / 128, MB), 256, 0, stream>>>(
                state, D, wc + off[19] + (long)i * D * dff + (long)dh * D, D,
                wc + off[20] + i * dff + dh, nullptr, hbuf, dh, nt, D);
            mgemm_k<false, true><<<dim3(2, MB), 256, 0, stream>>>(
                hbuf, dh, wc + off[21] + (long)i * dff * D + dh, dff, nullptr,
                posattn_b, posattn_b, D, nt, dh);
            if (have_posc && i + 1 < nlayers)
                ln_k<true><<<LB, 256, 0, stream>>>(posattn_b, wc + off[23] + i * D,
                    wc + off[24] + i * D, state, posc, posattn_b, nt);
            else
                ln_k<false><<<LB, 256, 0, stream>>>(posattn_b, wc + off[23] + i * D,
                    wc + off[24] + i * D, state, nullptr, nullptr, nt);
        }
    }

    finalize_k<<<(int)((osz - 4 + 255) / 256), 256, 0, stream>>>(
        state, (float*)d_out, osz);
}

// Round 10
// 2149.606 us; speedup vs baseline: 1.2726x; 1.1194x over previous
//
#include <hip/hip_runtime.h>

#define D 256
#define L_TOT 13294

typedef __attribute__((ext_vector_type(8))) __bf16 bf16x8;
typedef __attribute__((ext_vector_type(4))) float f32x4;
typedef __attribute__((ext_vector_type(2))) float f32x2;

__device__ __forceinline__ float bf2f(unsigned short u) {
    return __uint_as_float(((unsigned int)u) << 16);
}
__device__ __forceinline__ unsigned short f2bf(float f) {
    unsigned int u = __float_as_uint(f);
    u += 0x7FFFu + ((u >> 16) & 1u);   // round-to-nearest-even
    return (unsigned short)(u >> 16);
}
// two bf16 packed in a dword -> f32x2 {lo, hi}
__device__ __forceinline__ f32x2 bfpair(unsigned int d) {
    f32x2 r;
    r.x = __uint_as_float(d << 16);
    r.y = __uint_as_float(d & 0xFFFF0000u);
    return r;
}
__device__ __forceinline__ f32x2 fma2(f32x2 a, float w, f32x2 c) {
    return __builtin_elementwise_fma(a, (f32x2){w, w}, c);   // v_pk_fma_f32
}

// ---------------------------------------------------------------------------
// Dtype probe on level_embed: bf16 data -> ~100% sane exponents; fp32 read as
// halfwords -> ~60%. flag=1 means bf16 inputs.
// ---------------------------------------------------------------------------
__global__ void probe_k(const unsigned short* __restrict__ u, int n, int* __restrict__ flag)
{
    __shared__ int cnt;
    if (threadIdx.x == 0) cnt = 0;
    __syncthreads();
    int c = 0;
    for (int i = threadIdx.x; i < n; i += 256) {
        const int e = (u[i] >> 7) & 0xFF;
        if (e == 0 || (e >= 96 && e <= 150)) ++c;
    }
    atomicAdd(&cnt, c);
    __syncthreads();
    if (threadIdx.x == 0) *flag = (cnt * 10 > n * 9) ? 1 : 0;
}

__global__ __launch_bounds__(256) void convert_k(
    const void* __restrict__ src, unsigned short* __restrict__ dst, int n,
    const int* __restrict__ flag)
{
    const int i = blockIdx.x * 256 + threadIdx.x;
    if (i >= n) return;
    if (*flag) dst[i] = ((const unsigned short*)src)[i];
    else       dst[i] = f2bf(((const float*)src)[i]);
}

// Convert + transpose: src (L,K,N) -> dst (L,N,K) bf16.
__global__ __launch_bounds__(256) void convt_k(
    const void* __restrict__ src, unsigned short* __restrict__ dst,
    int K, int N, int L, const int* __restrict__ flag)
{
    const long e = (long)blockIdx.x * 256 + threadIdx.x;
    const long tot = (long)L * K * N;
    if (e >= tot) return;
    const int per = K * N;
    const int li = (int)(e / per);
    const int r  = (int)(e - (long)li * per);
    const int n  = r / K;
    const int k  = r - n * K;
    const long s = (long)li * per + (long)k * N + n;
    dst[e] = (*flag) ? ((const unsigned short*)src)[s]
                     : f2bf(((const float*)src)[s]);
}

// ---------------------------------------------------------------------------
// Flatten (B,D,H,W) src inputs -> state bf16 (tok,D).
// ---------------------------------------------------------------------------
__global__ __launch_bounds__(256) void flatten_k(
    const void* __restrict__ s0, const void* __restrict__ s1,
    const void* __restrict__ s2, const void* __restrict__ s3,
    const int* __restrict__ flag, unsigned short* __restrict__ state)
{
    const long e = (long)blockIdx.x * 256 + threadIdx.x;
    const int d = (int)(e & 255);
    const long tok = e >> 8;
    const int b = (int)(tok / L_TOT);
    const int t = (int)(tok - (long)b * L_TOT);
    const void *sp;
    int hw, idx;
    if (t < 10000)      { sp = s0; hw = 10000; idx = t;          }
    else if (t < 12500) { sp = s1; hw = 2500;  idx = t - 10000;  }
    else if (t < 13125) { sp = s2; hw = 625;   idx = t - 12500;  }
    else                { sp = s3; hw = 169;   idx = t - 13125;  }
    const long a = ((long)b * D + d) * hw + idx;
    state[e] = (*flag) ? ((const unsigned short*)sp)[a]
                       : f2bf(((const float*)sp)[a]);
}

// Layer-invariant pos precompute: posc = pos_input + level_embed (bf16).
__global__ __launch_bounds__(256) void posconst_k(
    const void* __restrict__ p0, const void* __restrict__ p1,
    const void* __restrict__ p2, const void* __restrict__ p3,
    const unsigned short* __restrict__ lev, const int* __restrict__ flag,
    unsigned short* __restrict__ posc)
{
    const long e = (long)blockIdx.x * 256 + threadIdx.x;
    const int d = (int)(e & 255);
    const long tok = e >> 8;
    const int b = (int)(tok / L_TOT);
    const int t = (int)(tok - (long)b * L_TOT);
    const void *pp;
    int hw, idx, l;
    if (t < 10000)      { pp = p0; hw = 10000; idx = t;          l = 0; }
    else if (t < 12500) { pp = p1; hw = 2500;  idx = t - 10000;  l = 1; }
    else if (t < 13125) { pp = p2; hw = 625;   idx = t - 12500;  l = 2; }
    else                { pp = p3; hw = 169;   idx = t - 13125;  l = 3; }
    const long a = ((long)b * D + d) * hw + idx;
    const float pv = (*flag) ? bf2f(((const unsigned short*)pp)[a])
                             : ((const float*)pp)[a];
    posc[e] = f2bf(pv + bf2f(lev[l * D + d]));
}

// q = x + posc, fully coalesced uint4 (8 bf16/thread). (layer-0 only)
__global__ __launch_bounds__(256) void addq_k(
    const unsigned short* __restrict__ x, const unsigned short* __restrict__ p,
    unsigned short* __restrict__ q, long n8)
{
    const long e = (long)blockIdx.x * 256 + threadIdx.x;
    if (e >= n8) return;
    const uint4 xv = ((const uint4*)x)[e];
    const uint4 pv = ((const uint4*)p)[e];
    uint4 o;
#define ADDPK(a, b) ({ const f32x2 fa = bfpair(a), fb = bfpair(b); \
        (unsigned int)f2bf(fb.x + fa.x) | ((unsigned int)f2bf(fb.y + fa.y) << 16); })
    o.x = ADDPK(xv.x, pv.x); o.y = ADDPK(xv.y, pv.y);
    o.z = ADDPK(xv.z, pv.z); o.w = ADDPK(xv.w, pv.w);
#undef ADDPK
    ((uint4*)q)[e] = o;
}

// Fallback (tight workspace): per-layer q = x + pos_input + level_embed.
__global__ __launch_bounds__(256) void posflat_k(
    const void* __restrict__ p0, const void* __restrict__ p1,
    const void* __restrict__ p2, const void* __restrict__ p3,
    const unsigned short* __restrict__ lev, const int* __restrict__ flag,
    const unsigned short* __restrict__ x, unsigned short* __restrict__ q)
{
    const long e = (long)blockIdx.x * 256 + threadIdx.x;
    const int d = (int)(e & 255);
    const long tok = e >> 8;
    const int b = (int)(tok / L_TOT);
    const int t = (int)(tok - (long)b * L_TOT);
    const void *pp;
    int hw, idx, l;
    if (t < 10000)      { pp = p0; hw = 10000; idx = t;          l = 0; }
    else if (t < 12500) { pp = p1; hw = 2500;  idx = t - 10000;  l = 1; }
    else if (t < 13125) { pp = p2; hw = 625;   idx = t - 12500;  l = 2; }
    else                { pp = p3; hw = 169;   idx = t - 13125;  l = 3; }
    const long a = ((long)b * D + d) * hw + idx;
    const float pv = (*flag) ? bf2f(((const unsigned short*)pp)[a])
                             : ((const float*)pp)[a];
    q[e] = f2bf(pv + bf2f(lev[l * D + d]) + bf2f(x[e]));
}

// ---------------------------------------------------------------------------
// MFMA GEMM core, single-buffered m97 structure, BK=64 (R7: BK=32 dbuf
// regressed; R3: BK=64 dbuf cost occupancy; this is the measured optimum).
// Tile 128x128, 4 waves (2x2). OPERANDS SWAPPED: acc = mfma(bfr, af, acc) ->
// lane holds row (l&15), 4 consecutive cols (l>>4)*4+r -> ushort4 epilogue.
// LDS XOR-swizzle in 16B groups (G4); global source pre-swizzled (rule #21).
// ---------------------------------------------------------------------------
template<bool RELU, bool RESID>
__device__ __forceinline__ void gemm_core(
    const unsigned short* __restrict__ A, int ldA,
    const unsigned short* __restrict__ Bt, int ldB,
    const unsigned short* __restrict__ bias,
    const unsigned short* resid,          // may alias out
    unsigned short* out, int ldO,
    long M, int K, int col0, long row0,
    unsigned short* As, unsigned short* Bs)
{
    const int tid = threadIdx.x;
    const int l  = tid & 63;
    const int w  = tid >> 6;
    const int wm = w >> 1, wn = w & 1;

    f32x4 acc[4][4];
#pragma unroll
    for (int i = 0; i < 4; ++i)
#pragma unroll
        for (int j = 0; j < 4; ++j) acc[i][j] = (f32x4){0.f, 0.f, 0.f, 0.f};

    const int sr = tid >> 3;
    const int sg = tid & 7;

    for (int k0 = 0; k0 < K; k0 += 64) {
#pragma unroll
        for (int i = 0; i < 4; ++i) {
            const int r = i * 32 + sr;
            long arow = row0 + r; if (arow >= M) arow = M - 1;   // clamp tail
            const int ke = k0 + ((sg ^ (r & 7)) << 3);           // pre-swizzled src
            const unsigned short* ga = A  + arow * (long)ldA + ke;
            const unsigned short* gb = Bt + (long)(col0 + r) * ldB + ke;
            __builtin_amdgcn_global_load_lds(
                (const __attribute__((address_space(1))) void*)ga,
                (__attribute__((address_space(3))) void*)(As + i * 2048 + w * 512),
                16, 0, 0);
            __builtin_amdgcn_global_load_lds(
                (const __attribute__((address_space(1))) void*)gb,
                (__attribute__((address_space(3))) void*)(Bs + i * 2048 + w * 512),
                16, 0, 0);
        }
        __syncthreads();    // drains vmcnt, tiles ready
#pragma unroll
        for (int ks = 0; ks < 2; ++ks) {
            const int cc  = ks * 4 + (l >> 4);
            const int swz = ((cc ^ (l & 7)) << 4);
            bf16x8 af[4], bfr[4];
#pragma unroll
            for (int mi = 0; mi < 4; ++mi) {
                const int ar = wm * 64 + mi * 16 + (l & 15);
                af[mi] = *(const bf16x8*)((const char*)As + ar * 128 + swz);
            }
#pragma unroll
            for (int ni = 0; ni < 4; ++ni) {
                const int br = wn * 64 + ni * 16 + (l & 15);
                bfr[ni] = *(const bf16x8*)((const char*)Bs + br * 128 + swz);
            }
#pragma unroll
            for (int mi = 0; mi < 4; ++mi)
#pragma unroll
                for (int ni = 0; ni < 4; ++ni)
                    acc[mi][ni] = __builtin_amdgcn_mfma_f32_16x16x32_bf16(
                        bfr[ni], af[mi], acc[mi][ni], 0, 0, 0);   // SWAPPED -> C^T frag
        }
        __syncthreads();    // compute done before next stage overwrites
    }

    // epilogue: lane holds row (l&15), 4 consecutive cols (l>>4)*4+r
#pragma unroll
    for (int mi = 0; mi < 4; ++mi) {
        const long rr = row0 + wm * 64 + mi * 16 + (l & 15);
        if (rr >= M) continue;
#pragma unroll
        for (int ni = 0; ni < 4; ++ni) {
            const int col = col0 + wn * 64 + ni * 16 + (l >> 4) * 4;
            f32x4 v = acc[mi][ni];
            if (bias) {
                const ushort4 b4 = *(const ushort4*)(bias + col);
                v[0] += bf2f(b4.x); v[1] += bf2f(b4.y);
                v[2] += bf2f(b4.z); v[3] += bf2f(b4.w);
            }
            if (RELU) {
                v[0] = fmaxf(v[0], 0.f); v[1] = fmaxf(v[1], 0.f);
                v[2] = fmaxf(v[2], 0.f); v[3] = fmaxf(v[3], 0.f);
            }
            if (RESID) {
                const ushort4 r4 = *(const ushort4*)(resid + rr * (long)ldO + col);
                v[0] += bf2f(r4.x); v[1] += bf2f(r4.y);
                v[2] += bf2f(r4.z); v[3] += bf2f(r4.w);
            }
            ushort4 o;
            o.x = f2bf(v[0]); o.y = f2bf(v[1]); o.z = f2bf(v[2]); o.w = f2bf(v[3]);
            *(ushort4*)(out + rr * (long)ldO + col) = o;
        }
    }
}

template<bool RELU, bool RESID>
__global__ __launch_bounds__(256, 3) void mgemm_k(
    const unsigned short* __restrict__ A, int ldA,
    const unsigned short* __restrict__ Bt, int ldB,
    const unsigned short* __restrict__ bias,
    const unsigned short* resid,
    unsigned short* out, int ldOut,
    long M, int K)
{
    __shared__ unsigned short As[8192];
    __shared__ unsigned short Bs[8192];
    gemm_core<RELU, RESID>(A, ldA, Bt, ldB, bias, resid, out, ldOut,
                           M, K, blockIdx.x * 128, (long)blockIdx.y * 128, As, Bs);
}

// Merged value + sampling-offsets + attn-logits (one dispatch; segment select
// is block-uniform). grid = dim3(5, MB): cols 0-1 value, 2-3 offsets, 4 logits.
__global__ __launch_bounds__(256, 3) void mgemm3_k(
    const unsigned short* __restrict__ state, const unsigned short* __restrict__ q,
    const unsigned short* __restrict__ Wv,  const unsigned short* __restrict__ bv,
    const unsigned short* __restrict__ Wso, const unsigned short* __restrict__ bso,
    const unsigned short* __restrict__ Waw, const unsigned short* __restrict__ baw,
    unsigned short* valo, unsigned short* offo, unsigned short* awo, long M)
{
    __shared__ unsigned short As[8192];
    __shared__ unsigned short Bs[8192];
    const int cx = blockIdx.x * 128;
    const long row0 = (long)blockIdx.y * 128;
    if (cx < 256)
        gemm_core<false, false>(state, D, Wv, D, bv, nullptr, valo, D,
                                M, D, cx, row0, As, Bs);
    else if (cx < 512)
        gemm_core<false, false>(q, D, Wso, D, bso, nullptr, offo, D,
                                M, D, cx - 256, row0, As, Bs);
    else
        gemm_core<false, false>(q, D, Waw, D, baw, nullptr, awo, 128,
                                M, D, 0, row0, As, Bs);
}

// ---------------------------------------------------------------------------
// GEMM + residual + LayerNorm fused (out = LN(resid + A@B + bias), optional
// q = bf16(out)+posc). Tile 64 rows x 256 cols; 4 waves each own a 64x64
// quadrant. LDS A 8KB + B 32KB + red 2KB -> 3 blocks/CU. NUMERICS: y rounded
// to bf16 BEFORE LN stats (bit-identical to separate ln_k over bf16 y).
// ---------------------------------------------------------------------------
template<bool QOUT>
__global__ __launch_bounds__(256, 3) void mgemmln_k(
    const unsigned short* __restrict__ A, int ldA,
    const unsigned short* __restrict__ Bt, int ldB,
    const unsigned short* __restrict__ bias,
    const unsigned short* resid,
    const unsigned short* __restrict__ gamma,
    const unsigned short* __restrict__ beta,
    unsigned short* outp,
    const unsigned short* __restrict__ posc,
    unsigned short* __restrict__ qout,
    long M, int K)
{
    __shared__ unsigned short As[64 * 64];      // 8 KB
    __shared__ unsigned short Bs[256 * 64];     // 32 KB
    __shared__ float red[2][4][4][16];          // [sum|sq][wave][mi][row16]
    const int tid = threadIdx.x;
    const int l = tid & 63;
    const int w = tid >> 6;
    const long row0 = (long)blockIdx.x * 64;

    f32x4 acc[4][4];
#pragma unroll
    for (int i = 0; i < 4; ++i)
#pragma unroll
        for (int j = 0; j < 4; ++j) acc[i][j] = (f32x4){0.f, 0.f, 0.f, 0.f};

    for (int k0 = 0; k0 < K; k0 += 64) {
#pragma unroll
        for (int i = 0; i < 10; ++i) {           // 2 rounds A, 8 rounds B
            const int c = i * 256 + tid;
            const unsigned short* gsrc;
            unsigned short* ldst;
            if (i < 2) {
                const int r = c >> 3, grp = c & 7;
                long ar = row0 + r; if (ar >= M) ar = M - 1;
                gsrc = A + ar * (long)ldA + (k0 + ((grp ^ (r & 7)) << 3));
                ldst = As + (c << 3);
            } else {
                const int r = (c >> 3) - 64, grp = c & 7;
                gsrc = Bt + (long)r * ldB + (k0 + ((grp ^ (r & 7)) << 3));
                ldst = Bs + ((c - 512) << 3);
            }
            __builtin_amdgcn_global_load_lds(
                (const __attribute__((address_space(1))) void*)gsrc,
                (__attribute__((address_space(3))) void*)ldst, 16, 0, 0);
        }
        __syncthreads();
#pragma unroll
        for (int ks = 0; ks < 2; ++ks) {
            const int cc = ks * 4 + (l >> 4);
            bf16x8 af[4], bfr[4];
#pragma unroll
            for (int mi = 0; mi < 4; ++mi) {
                const int ar = mi * 16 + (l & 15);
                af[mi] = *(const bf16x8*)((const char*)As + ar * 128 + ((cc ^ (ar & 7)) << 4));
            }
#pragma unroll
            for (int ni = 0; ni < 4; ++ni) {
                const int br = w * 64 + ni * 16 + (l & 15);
                bfr[ni] = *(const bf16x8*)((const char*)Bs + br * 128 + ((cc ^ (br & 7)) << 4));
            }
#pragma unroll
            for (int mi = 0; mi < 4; ++mi)
#pragma unroll
                for (int ni = 0; ni < 4; ++ni)
                    acc[mi][ni] = __builtin_amdgcn_mfma_f32_16x16x32_bf16(
                        bfr[ni], af[mi], acc[mi][ni], 0, 0, 0);
        }
        __syncthreads();
    }

    // ---- epilogue: y = bf16(gemm + bias + resid); LN stats over 256 cols ---
#pragma unroll
    for (int mi = 0; mi < 4; ++mi) {
        const long rr = row0 + mi * 16 + (l & 15);
        const long rrc = (rr < M) ? rr : (M - 1);
#pragma unroll
        for (int ni = 0; ni < 4; ++ni) {
            const int col = w * 64 + ni * 16 + (l >> 4) * 4;
            const ushort4 b4 = *(const ushort4*)(bias + col);
            const ushort4 r4 = *(const ushort4*)(resid + rrc * D + col);
            acc[mi][ni][0] = bf2f(f2bf(acc[mi][ni][0] + bf2f(b4.x) + bf2f(r4.x)));
            acc[mi][ni][1] = bf2f(f2bf(acc[mi][ni][1] + bf2f(b4.y) + bf2f(r4.y)));
            acc[mi][ni][2] = bf2f(f2bf(acc[mi][ni][2] + bf2f(b4.z) + bf2f(r4.z)));
            acc[mi][ni][3] = bf2f(f2bf(acc[mi][ni][3] + bf2f(b4.w) + bf2f(r4.w)));
        }
    }
#pragma unroll
    for (int mi = 0; mi < 4; ++mi) {
        float s = 0.f, qq = 0.f;
#pragma unroll
        for (int ni = 0; ni < 4; ++ni)
#pragma unroll
            for (int r = 0; r < 4; ++r) {
                const float v = acc[mi][ni][r];
                s += v; qq += v * v;
            }
        s += __shfl_xor(s, 16);  s += __shfl_xor(s, 32);
        qq += __shfl_xor(qq, 16); qq += __shfl_xor(qq, 32);
        if (l < 16) { red[0][w][mi][l] = s; red[1][w][mi][l] = qq; }
    }
    __syncthreads();
    float mean[4], rstd[4];
#pragma unroll
    for (int mi = 0; mi < 4; ++mi) {
        const int r16 = l & 15;
        const float s = red[0][0][mi][r16] + red[0][1][mi][r16]
                      + red[0][2][mi][r16] + red[0][3][mi][r16];
        const float qq = red[1][0][mi][r16] + red[1][1][mi][r16]
                       + red[1][2][mi][r16] + red[1][3][mi][r16];
        const float mn = s * (1.f / D);
        const float var = qq * (1.f / D) - mn * mn;
        mean[mi] = mn;
        rstd[mi] = rsqrtf(var + 1e-5f);
    }
#pragma unroll
    for (int mi = 0; mi < 4; ++mi) {
        const long rr = row0 + mi * 16 + (l & 15);
        if (rr >= M) continue;
#pragma unroll
        for (int ni = 0; ni < 4; ++ni) {
            const int col = w * 64 + ni * 16 + (l >> 4) * 4;
            const ushort4 g4 = *(const ushort4*)(gamma + col);
            const ushort4 e4 = *(const ushort4*)(beta + col);
            ushort4 o;
            o.x = f2bf((acc[mi][ni][0] - mean[mi]) * rstd[mi] * bf2f(g4.x) + bf2f(e4.x));
            o.y = f2bf((acc[mi][ni][1] - mean[mi]) * rstd[mi] * bf2f(g4.y) + bf2f(e4.y));
            o.z = f2bf((acc[mi][ni][2] - mean[mi]) * rstd[mi] * bf2f(g4.z) + bf2f(e4.z));
            o.w = f2bf((acc[mi][ni][3] - mean[mi]) * rstd[mi] * bf2f(g4.w) + bf2f(e4.w));
            *(ushort4*)(outp + rr * D + col) = o;
            if (QOUT) {
                const ushort4 p4 = *(const ushort4*)(posc + rr * D + col);
                ushort4 qo;
                qo.x = f2bf(bf2f(o.x) + bf2f(p4.x));
                qo.y = f2bf(bf2f(o.y) + bf2f(p4.y));
                qo.z = f2bf(bf2f(o.z) + bf2f(p4.z));
                qo.w = f2bf(bf2f(o.w) + bf2f(p4.w));
                *(ushort4*)(qout + rr * D + col) = qo;
            }
        }
    }
}

// ---------------------------------------------------------------------------
// Deformable sampling, 2 TOKENS PER BLOCK.
// Prep: all 256 threads active (tk = tid>>7, u = tid&127); tables at
// [tk][mu=lp*8+h][c^(lp&3)] (pair-preserving XOR, 4-way write alias).
// Gather: per token 128 threads = 4 slots x (8 heads x 4 chan-quads);
// lane handles 8 channels via uint4 (16B) loads -> HALF the load instrs and
// addresses of the 8B version; 32-bit offsets from uniform val base (27MB
// fits u32) -> saddr-form loads, no 64-bit addc chains. Slot-pair reduce via
// shfl_xor(32) in-register; cross-wave half via 1KB LDS. 16B final store.
// ---------------------------------------------------------------------------
__global__ __launch_bounds__(256) void sample_k(
    const unsigned short* __restrict__ off, const unsigned short* __restrict__ aw,
    const unsigned short* __restrict__ val, unsigned short* __restrict__ attn,
    long nt)
{
    __shared__ __align__(16) int   cidx[2][128][4];   // byte offsets into val
    __shared__ __align__(16) float cw[2][128][4];
    __shared__ __align__(16) float red[2][32][8];
    const int tid = threadIdx.x;

    // ---- prep: 2 tokens x 128 sample-entries, fully occupied -------------
    {
        const int tk = tid >> 7;
        const int u  = tid & 127;                 // u = h*16 + lp
        long tok = (long)blockIdx.x * 2 + tk;
        if (tok >= nt) tok = nt - 1;
        const int b = (int)(tok / L_TOT);
        const int t = (int)(tok - (long)b * L_TOT);
        const int lp = u & 15;
        const int mu = lp * 8 + (u >> 4);
        const int cswz = lp & 3;                  // pair-preserving bank swizzle
        // softmax over the 16 samples of this head (16-lane shfl groups)
        const float logit = bf2f(aw[tok * 128 + u]);
        float m = logit;
#pragma unroll
        for (int mk = 1; mk < 16; mk <<= 1) m = fmaxf(m, __shfl_xor(m, mk));
        const float e = expf(logit - m);
        float s = e;
#pragma unroll
        for (int mk = 1; mk < 16; mk <<= 1) s += __shfl_xor(s, mk);
        const float a = e / s;
        // token geometry
        int st0, W0;
        if (t < 10000)      { st0 = 0;     W0 = 100; }
        else if (t < 12500) { st0 = 10000; W0 = 50;  }
        else if (t < 13125) { st0 = 12500; W0 = 25;  }
        else                { st0 = 13125; W0 = 13;  }
        const int i0 = t - st0;
        const int yy = i0 / W0;
        const int xx = i0 - yy * W0;
        const float gx = (xx + 0.5f) / (float)W0;
        const float gy = (yy + 0.5f) / (float)W0;   // square levels
        // sample level
        const int lv = (u >> 2) & 3;
        const int Wv  = (lv == 0) ? 100 : (lv == 1) ? 50 : (lv == 2) ? 25 : 13;
        const int stl = (lv == 0) ? 0 : (lv == 1) ? 10000 : (lv == 2) ? 12500 : 13125;
        const unsigned int op = *(const unsigned int*)(off + tok * 256 + 2 * u);
        const float ox = bf2f((unsigned short)op);
        const float oy = bf2f((unsigned short)(op >> 16));
        const float px = (gx + ox / (float)Wv) * Wv - 0.5f;
        const float py = (gy + oy / (float)Wv) * Wv - 0.5f;
        const float fx = floorf(px), fy = floorf(py);
        const float wx1 = px - fx, wy1 = py - fy;
        const int x0 = (int)fx, y0 = (int)fy;
#pragma unroll
        for (int c = 0; c < 4; ++c) {
            const int xi = x0 + (c & 1);
            const int yi = y0 + (c >> 1);
            const float wgt = ((c & 1) ? wx1 : 1.f - wx1) * ((c >> 1) ? wy1 : 1.f - wy1);
            const bool ok = (xi >= 0) && (xi < Wv) && (yi >= 0) && (yi < Wv);
            cidx[tk][mu][c ^ cswz] = ok ? ((stl + yi * Wv + xi) << 9) : 0;   // *512 B
            cw[tk][mu][c ^ cswz]   = ok ? wgt * a : 0.f;
        }
    }
    __syncthreads();

    // ---- gather ----------------------------------------------------------
    const int tk = tid >> 7;
    long tok = (long)blockIdx.x * 2 + tk;
    if (tok >= nt) tok = nt - 1;
    const int b = (int)(tok / L_TOT);
    const int r = tid & 127;
    const int slot = r >> 5;                // 0..3 (2 per wave)
    const int l32 = r & 31;
    const int h  = l32 >> 2;                // head 0..7
    const int q4 = l32 & 3;                 // 16B channel quad (8 channels)
    const char* valc = (const char*)val;
    const unsigned int vbase = (unsigned int)b * (unsigned int)(L_TOT * 512)
                             + (unsigned int)(h * 64 + q4 * 16);
    f32x2 ac[4];
#pragma unroll
    for (int k = 0; k < 4; ++k) ac[k] = (f32x2){0.f, 0.f};
#pragma unroll
    for (int j = 0; j < 4; ++j) {
        const int mu = (j * 4 + slot) * 8 + h;
        const int4   ci = *(const int4*)(&cidx[tk][mu][0]);
        const float4 wv = *(const float4*)(&cw[tk][mu][0]);
        const uint4 d0 = *(const uint4*)(valc + (vbase + (unsigned int)ci.x));
        const uint4 d1 = *(const uint4*)(valc + (vbase + (unsigned int)ci.y));
        const uint4 d2 = *(const uint4*)(valc + (vbase + (unsigned int)ci.z));
        const uint4 d3 = *(const uint4*)(valc + (vbase + (unsigned int)ci.w));
        ac[0] = fma2(bfpair(d0.x), wv.x, ac[0]); ac[1] = fma2(bfpair(d0.y), wv.x, ac[1]);
        ac[2] = fma2(bfpair(d0.z), wv.x, ac[2]); ac[3] = fma2(bfpair(d0.w), wv.x, ac[3]);
        ac[0] = fma2(bfpair(d1.x), wv.y, ac[0]); ac[1] = fma2(bfpair(d1.y), wv.y, ac[1]);
        ac[2] = fma2(bfpair(d1.z), wv.y, ac[2]); ac[3] = fma2(bfpair(d1.w), wv.y, ac[3]);
        ac[0] = fma2(bfpair(d2.x), wv.z, ac[0]); ac[1] = fma2(bfpair(d2.y), wv.z, ac[1]);
        ac[2] = fma2(bfpair(d2.z), wv.z, ac[2]); ac[3] = fma2(bfpair(d2.w), wv.z, ac[3]);
        ac[0] = fma2(bfpair(d3.x), wv.w, ac[0]); ac[1] = fma2(bfpair(d3.y), wv.w, ac[1]);
        ac[2] = fma2(bfpair(d3.z), wv.w, ac[2]); ac[3] = fma2(bfpair(d3.w), wv.w, ac[3]);
    }
    // slot-pair reduce in-register (lane l <-> l^32 is the same (h,q4))
#pragma unroll
    for (int k = 0; k < 4; ++k) {
        ac[k].x += __shfl_xor(ac[k].x, 32);
        ac[k].y += __shfl_xor(ac[k].y, 32);
    }
    // cross-wave half: wave1 (slots 2|3) lanes 0..31 publish, wave0 adds
    if (r >= 64 && r < 96) {
#pragma unroll
        for (int k = 0; k < 4; ++k) {
            red[tk][l32][2 * k]     = ac[k].x;
            red[tk][l32][2 * k + 1] = ac[k].y;
        }
    }
    __syncthreads();
    if (r < 32) {
        uint4 o;
        unsigned int* op = &o.x;
#pragma unroll
        for (int k = 0; k < 4; ++k) {
            const float v0 = ac[k].x + red[tk][l32][2 * k];
            const float v1 = ac[k].y + red[tk][l32][2 * k + 1];
            op[k] = (unsigned int)f2bf(v0) | ((unsigned int)f2bf(v1) << 16);
        }
        *(uint4*)(attn + tok * 256 + h * 32 + q4 * 8) = o;
    }
}

// ---------------------------------------------------------------------------
// LayerNorm over D=256 (fallback path only). Block = 4 waves = 4 tokens.
// ---------------------------------------------------------------------------
template<bool QOUT>
__global__ __launch_bounds__(256) void ln_k(
    const unsigned short* __restrict__ y,
    const unsigned short* __restrict__ g, const unsigned short* __restrict__ bb,
    unsigned short* __restrict__ out,
    const unsigned short* __restrict__ posc, unsigned short* __restrict__ qout,
    long nt)
{
    const int wv = threadIdx.x >> 6;
    const int lane = threadIdx.x & 63;
    const long tok = (long)blockIdx.x * 4 + wv;
    if (tok >= nt) return;
    const ushort4 v4 = *(const ushort4*)(y + tok * D + lane * 4);
    const float v0 = bf2f(v4.x), v1 = bf2f(v4.y), v2 = bf2f(v4.z), v3 = bf2f(v4.w);
    float s = v0 + v1 + v2 + v3;
#pragma unroll
    for (int m = 1; m < 64; m <<= 1) s += __shfl_xor(s, m);
    const float mean = s * (1.f / D);
    const float d0 = v0 - mean, d1 = v1 - mean, d2 = v2 - mean, d3 = v3 - mean;
    float q = d0 * d0 + d1 * d1 + d2 * d2 + d3 * d3;
#pragma unroll
    for (int m = 1; m < 64; m <<= 1) q += __shfl_xor(q, m);
    const float rstd = rsqrtf(q * (1.f / D) + 1e-5f);
    const int c0 = lane * 4;
    ushort4 o;
    o.x = f2bf(d0 * rstd * bf2f(g[c0 + 0]) + bf2f(bb[c0 + 0]));
    o.y = f2bf(d1 * rstd * bf2f(g[c0 + 1]) + bf2f(bb[c0 + 1]));
    o.z = f2bf(d2 * rstd * bf2f(g[c0 + 2]) + bf2f(bb[c0 + 2]));
    o.w = f2bf(d3 * rstd * bf2f(g[c0 + 3]) + bf2f(bb[c0 + 3]));
    *(ushort4*)(out + tok * D + c0) = o;
    if (QOUT) {
        const ushort4 p4 = *(const ushort4*)(posc + tok * D + c0);
        ushort4 qo;
        qo.x = f2bf(bf2f(o.x) + bf2f(p4.x));
        qo.y = f2bf(bf2f(o.y) + bf2f(p4.y));
        qo.z = f2bf(bf2f(o.z) + bf2f(p4.z));
        qo.w = f2bf(bf2f(o.w) + bf2f(p4.w));
        *(ushort4*)(qout + tok * D + c0) = qo;
    }
}

// ---------------------------------------------------------------------------
// Finalize: OUTPUT IS FP32.
// ---------------------------------------------------------------------------
__global__ __launch_bounds__(256) void finalize_k(
    const unsigned short* __restrict__ state, float* __restrict__ out, long osz)
{
    const long e = (long)blockIdx.x * 256 + threadIdx.x;
    const long n0 = osz - 4;
    if (e < n0) out[e] = bf2f(state[e]);
    if (e < 4) {
        const float st[4] = {0.f, 10000.f, 12500.f, 13125.f};
        out[n0 + e] = st[e];
    }
}

extern "C" void kernel_launch(void* const* d_in, const int* in_sizes, int n_in,
                              void* d_out, int out_size, void* d_ws, size_t ws_size,
                              hipStream_t stream)
{
    (void)n_in;
    const long osz = (long)out_size;
    const long nt = (osz - 4) / D;                      // total tokens
    const int nlayers = in_sizes[9] / (D * D);          // so_w: (NL, 256, 256)
    const int dff = in_sizes[19] / (nlayers * D);       // f1_w: (NL, 256, DFF)

    char* ws = (char*)d_ws;
    int* flag = (int*)ws;  ws += 256;
    unsigned short* wc = (unsigned short*)ws;           // canonical bf16 weights
    long off[25]; long acc_off = 0;
    for (int i = 8; i <= 24; ++i) { off[i] = acc_off; acc_off += in_sizes[i]; }
    ws += ((acc_off * 2 + 255) / 256) * 256;
    const size_t SZ_BF = (size_t)nt * D * 2;
    unsigned short* state     = (unsigned short*)ws;  ws += SZ_BF;  // running src
    unsigned short* val_b     = (unsigned short*)ws;  ws += SZ_BF;  // value / h lo
    unsigned short* offy_b    = (unsigned short*)ws;  ws += SZ_BF;  // offsets,y / h hi
    unsigned short* posattn_b = (unsigned short*)ws;  ws += SZ_BF;  // q, attn
    unsigned short* aw_b      = (unsigned short*)ws;  ws += (size_t)nt * 128 * 2;
    unsigned short* hbuf = val_b;   // [nt][dff/2] spans val_b..offy_b (contiguous)

    // guarded extras: +27 MB posc (layer-invariant pos), +109 MB full-width h
    const size_t used_base = (size_t)((char*)aw_b - (char*)d_ws) + (size_t)nt * 128 * 2;
    const bool have_posc  = (ws_size >= used_base + SZ_BF);
    const bool have_hfull = (ws_size >= used_base + SZ_BF + 4 * SZ_BF);
    unsigned short* posc  = (unsigned short*)((char*)d_ws + used_base);
    unsigned short* hfull = (unsigned short*)((char*)d_ws + used_base + SZ_BF);

    probe_k<<<1, 256, 0, stream>>>((const unsigned short*)d_in[8], in_sizes[8], flag);

    // vectors/biases: plain convert
    const int vecIdx[11] = {8, 10, 12, 14, 16, 17, 18, 20, 22, 23, 24};
    for (int j = 0; j < 11; ++j) {
        const int i = vecIdx[j];
        convert_k<<<(in_sizes[i] + 255) / 256, 256, 0, stream>>>(
            d_in[i], wc + off[i], in_sizes[i], flag);
    }
    // matrices: convert + transpose to [N][K] for MFMA B-fragments
    const int matIdx[6] = {9, 11, 13, 15, 19, 21};
    const int matK[6]   = {D, D, D, D, D, dff};
    const int matN[6]   = {D, 128, D, D, dff, D};
    for (int j = 0; j < 6; ++j) {
        const int i = matIdx[j];
        convt_k<<<(in_sizes[i] + 255) / 256, 256, 0, stream>>>(
            d_in[i], wc + off[i], matK[j], matN[j], nlayers, flag);
    }

    flatten_k<<<(int)nt, 256, 0, stream>>>(
        d_in[0], d_in[2], d_in[4], d_in[6], flag, state);
    if (have_posc)
        posconst_k<<<(int)nt, 256, 0, stream>>>(
            d_in[1], d_in[3], d_in[5], d_in[7], wc + off[8], flag, posc);

    const int MB = (int)((nt + 127) / 128);
    const int FB = (int)((nt + 63) / 64);
    const int SB = (int)((nt + 1) / 2);         // sample: 2 tokens/block
    const int LB = (int)((nt + 3) / 4);
    const long n8 = (long)nt * D / 8;
    const int AB = (int)((n8 + 255) / 256);
    const int dh = dff / 2;                     // 512: fallback FFN split

    if (have_posc)                              // layer-0 q
        addq_k<<<AB, 256, 0, stream>>>(state, posc, posattn_b, n8);

    for (int i = 0; i < nlayers; ++i) {
        if (!have_posc)
            posflat_k<<<(int)nt, 256, 0, stream>>>(
                d_in[1], d_in[3], d_in[5], d_in[7], wc + off[8], flag, state, posattn_b);
        // merged: value (cols 0-255) | offsets (256-511) | logits (512-639)
        mgemm3_k<<<dim3(5, MB), 256, 0, stream>>>(
            state, posattn_b,
            wc + off[13] + (long)i * D * D,   wc + off[14] + i * D,
            wc + off[9]  + (long)i * D * 256, wc + off[10] + i * 256,
            wc + off[11] + (long)i * D * 128, wc + off[12] + i * 128,
            val_b, offy_b, aw_b, nt);
        sample_k<<<SB, 256, 0, stream>>>(offy_b, aw_b, val_b, posattn_b, nt);
        if (have_hfull) {
            // out-proj + resid + LN1 fused -> state (in place)
            mgemmln_k<false><<<FB, 256, 0, stream>>>(
                posattn_b, D, wc + off[15] + (long)i * D * D, D, wc + off[16] + i * D,
                state, wc + off[17] + i * D, wc + off[18] + i * D, state,
                nullptr, nullptr, nt, D);
            // full-width FFN: h = relu(x@W1+b1) [nt][1024]
            mgemm_k<true, false><<<dim3(dff / 128, MB), 256, 0, stream>>>(
                state, D, wc + off[19] + (long)i * D * dff, D, wc + off[20] + i * dff,
                nullptr, hfull, dff, nt, D);
            // f2 (K=1024) + resid + LN2 (+ next-layer q) fused -> state
            if (have_posc && i + 1 < nlayers)
                mgemmln_k<true><<<FB, 256, 0, stream>>>(
                    hfull, dff, wc + off[21] + (long)i * dff * D, dff,
                    wc + off[22] + i * D, state,
                    wc + off[23] + i * D, wc + off[24] + i * D, state,
                    posc, posattn_b, nt, dff);
            else
                mgemmln_k<false><<<FB, 256, 0, stream>>>(
                    hfull, dff, wc + off[21] + (long)i * dff * D, dff,
                    wc + off[22] + i * D, state,
                    wc + off[23] + i * D, wc + off[24] + i * D, state,
                    nullptr, nullptr, nt, dff);
        } else {
            mgemm_k<false, true><<<dim3(2, MB), 256, 0, stream>>>(  // out-proj + resid
                posattn_b, D, wc + off[15] + (long)i * D * D, D, wc + off[16] + i * D,
                state, offy_b, D, nt, D);
            ln_k<false><<<LB, 256, 0, stream>>>(offy_b, wc + off[17] + i * D,
                wc + off[18] + i * D, state, nullptr, nullptr, nt);
            // fallback: FFN as 2 half-dff passes through hbuf (val_b+offy_b)
            mgemm_k<true, false><<<dim3(dh / 128, MB), 256, 0, stream>>>(
                state, D, wc + off[19] + (long)i * D * dff, D, wc + off[20] + i * dff,
                nullptr, hbuf, dh, nt, D);
            mgemm_k<false, true><<<dim3(2, MB), 256, 0, stream>>>(
                hbuf, dh, wc + off[21] + (long)i * dff * D, dff, wc + off[22] + i * D,
                state, posattn_b, D, nt, dh);
            mgemm_k<true, false><<<dim3(dh / 128, MB), 256, 0, stream>>>(
                state, D, wc + off[19] + (long)i * D * dff + (long)dh * D, D,
                wc + off[20] + i * dff + dh, nullptr, hbuf, dh, nt, D);
            mgemm_k<false, true><<<dim3(2, MB), 256, 0, stream>>>(
                hbuf, dh, wc + off[21] + (long)i * dff * D + dh, dff, nullptr,
                posattn_b, posattn_b, D, nt, dh);
            if (have_posc && i + 1 < nlayers)
                ln_k<true><<<LB, 256, 0, stream>>>(posattn_b, wc + off[23] + i * D,
                    wc + off[24] + i * D, state, posc, posattn_b, nt);
            else
                ln_k<false><<<LB, 256, 0, stream>>>(posattn_b, wc + off[23] + i * D,
                    wc + off[24] + i * D, state, nullptr, nullptr, nt);
        }
    }

    finalize_k<<<(int)((osz - 4 + 255) / 256), 256, 0, stream>>>(
        state, (float*)d_out, osz);
}